// Round 5
// baseline (173.852 us; speedup 1.0000x reference)
//
#include <hip/hip_runtime.h>
#include <math.h>

#define EPSV 1e-6f
#define MAX_NORM (1.0f - 1e-3f)

typedef __attribute__((ext_vector_type(8))) short short8;   // 8 bf16 = 4 VGPRs
typedef __attribute__((ext_vector_type(4))) float f32x4;    // MFMA acc

// f32 -> bf16 (round-to-nearest-even), returns raw 16-bit pattern
__device__ inline ushort f32_to_bf16(float f) {
    union { float f; uint32_t u; } cv;
    cv.f = f;
    uint32_t u = cv.u;
    u += 0x7FFFu + ((u >> 16) & 1u);
    return (ushort)(u >> 16);
}

// async global -> LDS, 16 bytes per lane (dest = uniform base + lane*16)
__device__ inline void glds16(const ushort* gsrc, ushort* ldsdst) {
    auto* g = (const __attribute__((address_space(1))) uint32_t*)gsrc;
    auto* l = (__attribute__((address_space(3))) uint32_t*)ldsdst;
    __builtin_amdgcn_global_load_lds(g, l, 16, 0, 0);
}

// ---------------------------------------------------------------------------
// Kernel 1: expmap0 + clip for embeddings. One wave (64 lanes) per row, D=512.
// ---------------------------------------------------------------------------
__global__ void rows_emb_kernel(const float* __restrict__ emb,
                                const float* __restrict__ logc,
                                float* __restrict__ xh,
                                ushort* __restrict__ xbf,
                                float* __restrict__ x2raw,
                                float* __restrict__ dxv) {
    const int D = 512;
    const int row = blockIdx.x;
    const int lane = threadIdx.x;   // 0..63

    const float4* r4 = (const float4*)(emb + (size_t)row * D);
    float4 a = r4[2 * lane];
    float4 b = r4[2 * lane + 1];

    float ss = a.x * a.x + a.y * a.y + a.z * a.z + a.w * a.w
             + b.x * b.x + b.y * b.y + b.z * b.z + b.w * b.w;
#pragma unroll
    for (int off = 32; off > 0; off >>= 1) ss += __shfl_xor(ss, off, 64);

    const float c  = expf(logc[0]);
    const float sc = sqrtf(c);

    const float tn    = sqrtf(ss);
    const float vn    = fmaxf(tn, EPSV);
    const float coeff = tanhf(sc * vn) / (sc * vn);
    const float pre   = coeff * tn;
    const float fac   = fminf(MAX_NORM / fmaxf(pre, EPSV), 1.0f);
    const float scale = coeff * fac;

    float4 oa, ob;
    oa.x = a.x * scale; oa.y = a.y * scale; oa.z = a.z * scale; oa.w = a.w * scale;
    ob.x = b.x * scale; ob.y = b.y * scale; ob.z = b.z * scale; ob.w = b.w * scale;

    float4* o4 = (float4*)(xh + (size_t)row * D);
    o4[2 * lane]     = oa;
    o4[2 * lane + 1] = ob;

    union { ushort u[8]; uint4 v; } pk;
    pk.u[0] = f32_to_bf16(oa.x); pk.u[1] = f32_to_bf16(oa.y);
    pk.u[2] = f32_to_bf16(oa.z); pk.u[3] = f32_to_bf16(oa.w);
    pk.u[4] = f32_to_bf16(ob.x); pk.u[5] = f32_to_bf16(ob.y);
    pk.u[6] = f32_to_bf16(ob.z); pk.u[7] = f32_to_bf16(ob.w);
    ((uint4*)(xbf + (size_t)row * D))[lane] = pk.v;

    if (lane == 0) {
        const float sq = scale * scale * ss;
        x2raw[row] = sq;
        dxv[row]   = 1.0f - c * fminf(sq, MAX_NORM * MAX_NORM);
    }
}

// ---------------------------------------------------------------------------
// Kernel 2: clip-only for centroids. One wave per row, D=512.
// ---------------------------------------------------------------------------
__global__ void rows_cen_kernel(const float* __restrict__ cen,
                                const float* __restrict__ logc,
                                float* __restrict__ ch,
                                ushort* __restrict__ cbf,
                                float* __restrict__ y2raw,
                                float* __restrict__ dyv) {
    const int D = 512;
    const int row = blockIdx.x;
    const int lane = threadIdx.x;

    const float4* r4 = (const float4*)(cen + (size_t)row * D);
    float4 a = r4[2 * lane];
    float4 b = r4[2 * lane + 1];

    float ss = a.x * a.x + a.y * a.y + a.z * a.z + a.w * a.w
             + b.x * b.x + b.y * b.y + b.z * b.z + b.w * b.w;
#pragma unroll
    for (int off = 32; off > 0; off >>= 1) ss += __shfl_xor(ss, off, 64);

    const float c = expf(logc[0]);

    const float tn    = sqrtf(ss);
    const float scale = fminf(MAX_NORM / fmaxf(tn, EPSV), 1.0f);

    float4 oa, ob;
    oa.x = a.x * scale; oa.y = a.y * scale; oa.z = a.z * scale; oa.w = a.w * scale;
    ob.x = b.x * scale; ob.y = b.y * scale; ob.z = b.z * scale; ob.w = b.w * scale;

    float4* o4 = (float4*)(ch + (size_t)row * D);
    o4[2 * lane]     = oa;
    o4[2 * lane + 1] = ob;

    union { ushort u[8]; uint4 v; } pk;
    pk.u[0] = f32_to_bf16(oa.x); pk.u[1] = f32_to_bf16(oa.y);
    pk.u[2] = f32_to_bf16(oa.z); pk.u[3] = f32_to_bf16(oa.w);
    pk.u[4] = f32_to_bf16(ob.x); pk.u[5] = f32_to_bf16(ob.y);
    pk.u[6] = f32_to_bf16(ob.z); pk.u[7] = f32_to_bf16(ob.w);
    ((uint4*)(cbf + (size_t)row * D))[lane] = pk.v;

    if (lane == 0) {
        const float sq = scale * scale * ss;
        y2raw[row] = sq;
        dyv[row]   = 1.0f - c * fminf(sq, MAX_NORM * MAX_NORM);
    }
}

// ---------------------------------------------------------------------------
// Kernel 3: bf16 MFMA GEMM + Poincare epilogue.
// 128x128 tile, BKT=32, DOUBLE-BUFFERED fragment-order LDS, prefetch dist 1.
// Per K-step: issue next tile's global_load_lds FIRST, then ds_read+MFMA of
// current tile, then one __syncthreads() (vmcnt(0)+barrier) — the prefetch
// latency hides under the MFMA phase (T3 minimum 2-phase recipe).
//
// LDS per buffer: 8 subtiles x 1KB per matrix, subtile s = rowgroup (16 rows
// x 32 k) in exact fragment order (lane l -> row l&15, k (l>>4)*8), staged
// via per-lane pre-swizzled global source + linear LDS dest (rule #21).
// ds_read is uniform_base + lane*16B: zero bank conflicts.
// ---------------------------------------------------------------------------
#define BM 128
#define BN 128
#define BKT 32

__global__ __launch_bounds__(256)
void gemm_epi_kernel(const ushort* __restrict__ Abf,   // M x K bf16
                     const ushort* __restrict__ Bbf,   // N x K bf16
                     const float* __restrict__ x2raw,
                     const float* __restrict__ dxv,
                     const float* __restrict__ y2raw,
                     const float* __restrict__ dyv,
                     const float* __restrict__ logc,
                     float* __restrict__ out,          // M x N
                     int M, int N, int K) {
    __shared__ ushort As[2][BM * BKT];   // 2 x 8 KB
    __shared__ ushort Bs[2][BN * BKT];   // 2 x 8 KB

    const int tid  = threadIdx.x;
    const int lane = tid & 63;
    const int wid  = tid >> 6;
    const int wm   = wid >> 1;     // 0..1
    const int wn   = wid & 1;      // 0..1

    const int bm = blockIdx.y;
    const int bn = blockIdx.x;

    const ushort* Ab = Abf + (size_t)bm * BM * K;
    const ushort* Bb = Bbf + (size_t)bn * BN * K;

    f32x4 acc[4][4];
#pragma unroll
    for (int m = 0; m < 4; m++)
#pragma unroll
        for (int n = 0; n < 4; n++) acc[m][n] = (f32x4){0.f, 0.f, 0.f, 0.f};

    // Per-lane fragment-order source offset within a 16x32 subtile.
    const size_t fragoff = (size_t)(lane & 15) * K + ((lane >> 4) * 8);

    // Stage one K-tile (BKT=32) into buffer p: 8 subtiles per matrix,
    // wave w covers subtiles 2w and 2w+1 (2 A-calls + 2 B-calls).
    auto stage = [&](int p, int k0) {
#pragma unroll
        for (int j = 0; j < 2; j++) {
            const int s = wid * 2 + j;
            const size_t goff = (size_t)(s * 16) * K + k0 + fragoff;
            glds16(Ab + goff, &As[p][s * 512]);
            glds16(Bb + goff, &Bs[p][s * 512]);
        }
    };

    stage(0, 0);
    __syncthreads();                 // drain prologue loads

    const int NT = K / BKT;          // 16
    int p = 0;
    for (int t = 0; t < NT; t++) {
        if (t + 1 < NT) stage(p ^ 1, (t + 1) * BKT);   // prefetch next tile

        short8 af[4], bfr[4];
#pragma unroll
        for (int m = 0; m < 4; m++)
            af[m] = *(const short8*)(&As[p][(wm * 4 + m) * 512 + lane * 8]);
#pragma unroll
        for (int n = 0; n < 4; n++)
            bfr[n] = *(const short8*)(&Bs[p][(wn * 4 + n) * 512 + lane * 8]);
#pragma unroll
        for (int m = 0; m < 4; m++)
#pragma unroll
            for (int n = 0; n < 4; n++)
                acc[m][n] = __builtin_amdgcn_mfma_f32_16x16x32_bf16(
                    af[m], bfr[n], acc[m][n], 0, 0, 0);

        // vmcnt(0)+lgkmcnt(0)+barrier: prefetch landed (had MFMA phase to fly),
        // and everyone's ds_reads of buf p are retired before it's overwritten.
        if (t + 1 < NT) __syncthreads();
        p ^= 1;
    }

    // Epilogue: t = max(2c*diff2/denom, eps); dist = log(1+t+sqrt(t(t+2)))/sqrt(c)
    const float c   = expf(logc[0]);
    const float rsc = 1.0f / sqrtf(c);
    const int lr = lane & 15;
    const int lg = lane >> 4;

#pragma unroll
    for (int n = 0; n < 4; n++) {
        const int gc = bn * BN + wn * 64 + n * 16 + lr;
        const float ry = y2raw[gc];
        const float dy = dyv[gc];
#pragma unroll
        for (int m = 0; m < 4; m++) {
            const int gr0 = bm * BM + wm * 64 + m * 16 + lg * 4;
#pragma unroll
            for (int r = 0; r < 4; r++) {
                const int gr = gr0 + r;
                const float rx = x2raw[gr];
                const float dx = dxv[gr];
                const float xy = acc[m][n][r];
                const float diff2 = rx + ry - 2.0f * xy;
                const float rden = __builtin_amdgcn_rcpf(fmaxf(dx * dy, EPSV));
                float t = fmaxf(2.0f * c * diff2 * rden, EPSV);
                const float d =
                    __logf(1.0f + t + __builtin_amdgcn_sqrtf(t * (t + 2.0f))) * rsc;
                out[(size_t)gr * N + gc] = d;
            }
        }
    }
}

// ---------------------------------------------------------------------------
extern "C" void kernel_launch(void* const* d_in, const int* in_sizes, int n_in,
                              void* d_out, int out_size, void* d_ws, size_t ws_size,
                              hipStream_t stream) {
    const float* emb  = (const float*)d_in[0];   // (B, D) f32
    const float* logc = (const float*)d_in[1];   // scalar f32
    const float* cen  = (const float*)d_in[2];   // (C, D) f32

    const int D = 512;
    const int B = in_sizes[0] / D;   // 8192
    const int C = in_sizes[2] / D;   // 4096

    float* out   = (float*)d_out;
    float* dists = out;                          // B*C
    float* xh    = out + (size_t)B * C;          // B*D
    float* ch    = xh + (size_t)B * D;           // C*D

    char* ws = (char*)d_ws;
    size_t off = 0;
    auto alloc = [&](size_t bytes) -> char* {
        char* p = ws + off;
        off += (bytes + 255) & ~(size_t)255;
        return p;
    };
    ushort* xbf   = (ushort*)alloc((size_t)B * D * sizeof(ushort));
    ushort* cbf   = (ushort*)alloc((size_t)C * D * sizeof(ushort));
    float*  x2raw = (float*)alloc((size_t)B * sizeof(float));
    float*  dxv   = (float*)alloc((size_t)B * sizeof(float));
    float*  y2raw = (float*)alloc((size_t)C * sizeof(float));
    float*  dyv   = (float*)alloc((size_t)C * sizeof(float));

    rows_emb_kernel<<<B, 64, 0, stream>>>(emb, logc, xh, xbf, x2raw, dxv);
    rows_cen_kernel<<<C, 64, 0, stream>>>(cen, logc, ch, cbf, y2raw, dyv);

    dim3 grid(C / BN, B / BM);   // natural order: bn fastest (good XCD locality)
    gemm_epi_kernel<<<grid, 256, 0, stream>>>(xbf, cbf, x2raw, dxv, y2raw, dyv,
                                              logc, dists, B, C, D);
}

// Round 6
// 116.684 us; speedup vs baseline: 1.4899x; 1.4899x over previous
//
#include <hip/hip_runtime.h>
#include <math.h>

#define EPSV 1e-6f
#define MAX_NORM (1.0f - 1e-3f)

typedef __attribute__((ext_vector_type(8))) short short8;   // 8 bf16 = 4 VGPRs
typedef __attribute__((ext_vector_type(4))) float f32x4;    // MFMA acc

// f32 -> bf16 (round-to-nearest-even), returns raw 16-bit pattern
__device__ inline ushort f32_to_bf16(float f) {
    union { float f; uint32_t u; } cv;
    cv.f = f;
    uint32_t u = cv.u;
    u += 0x7FFFu + ((u >> 16) & 1u);
    return (ushort)(u >> 16);
}

// async global -> LDS, 16 bytes per lane (dest = uniform base + lane*16)
__device__ inline void glds16(const ushort* gsrc, ushort* ldsdst) {
    auto* g = (const __attribute__((address_space(1))) uint32_t*)gsrc;
    auto* l = (__attribute__((address_space(3))) uint32_t*)ldsdst;
    __builtin_amdgcn_global_load_lds(g, l, 16, 0, 0);
}

// ---------------------------------------------------------------------------
// Kernel 1: expmap0 + clip for embeddings. One wave (64 lanes) per row, D=512.
// ---------------------------------------------------------------------------
__global__ void rows_emb_kernel(const float* __restrict__ emb,
                                const float* __restrict__ logc,
                                float* __restrict__ xh,
                                ushort* __restrict__ xbf,
                                float* __restrict__ x2raw,
                                float* __restrict__ dxv) {
    const int D = 512;
    const int row = blockIdx.x;
    const int lane = threadIdx.x;   // 0..63

    const float4* r4 = (const float4*)(emb + (size_t)row * D);
    float4 a = r4[2 * lane];
    float4 b = r4[2 * lane + 1];

    float ss = a.x * a.x + a.y * a.y + a.z * a.z + a.w * a.w
             + b.x * b.x + b.y * b.y + b.z * b.z + b.w * b.w;
#pragma unroll
    for (int off = 32; off > 0; off >>= 1) ss += __shfl_xor(ss, off, 64);

    const float c  = expf(logc[0]);
    const float sc = sqrtf(c);

    const float tn    = sqrtf(ss);
    const float vn    = fmaxf(tn, EPSV);
    const float coeff = tanhf(sc * vn) / (sc * vn);
    const float pre   = coeff * tn;
    const float fac   = fminf(MAX_NORM / fmaxf(pre, EPSV), 1.0f);
    const float scale = coeff * fac;

    float4 oa, ob;
    oa.x = a.x * scale; oa.y = a.y * scale; oa.z = a.z * scale; oa.w = a.w * scale;
    ob.x = b.x * scale; ob.y = b.y * scale; ob.z = b.z * scale; ob.w = b.w * scale;

    float4* o4 = (float4*)(xh + (size_t)row * D);
    o4[2 * lane]     = oa;
    o4[2 * lane + 1] = ob;

    union { ushort u[8]; uint4 v; } pk;
    pk.u[0] = f32_to_bf16(oa.x); pk.u[1] = f32_to_bf16(oa.y);
    pk.u[2] = f32_to_bf16(oa.z); pk.u[3] = f32_to_bf16(oa.w);
    pk.u[4] = f32_to_bf16(ob.x); pk.u[5] = f32_to_bf16(ob.y);
    pk.u[6] = f32_to_bf16(ob.z); pk.u[7] = f32_to_bf16(ob.w);
    ((uint4*)(xbf + (size_t)row * D))[lane] = pk.v;

    if (lane == 0) {
        const float sq = scale * scale * ss;
        x2raw[row] = sq;
        dxv[row]   = 1.0f - c * fminf(sq, MAX_NORM * MAX_NORM);
    }
}

// ---------------------------------------------------------------------------
// Kernel 2: clip-only for centroids. One wave per row, D=512.
// ---------------------------------------------------------------------------
__global__ void rows_cen_kernel(const float* __restrict__ cen,
                                const float* __restrict__ logc,
                                float* __restrict__ ch,
                                ushort* __restrict__ cbf,
                                float* __restrict__ y2raw,
                                float* __restrict__ dyv) {
    const int D = 512;
    const int row = blockIdx.x;
    const int lane = threadIdx.x;

    const float4* r4 = (const float4*)(cen + (size_t)row * D);
    float4 a = r4[2 * lane];
    float4 b = r4[2 * lane + 1];

    float ss = a.x * a.x + a.y * a.y + a.z * a.z + a.w * a.w
             + b.x * b.x + b.y * b.y + b.z * b.z + b.w * b.w;
#pragma unroll
    for (int off = 32; off > 0; off >>= 1) ss += __shfl_xor(ss, off, 64);

    const float c = expf(logc[0]);

    const float tn    = sqrtf(ss);
    const float scale = fminf(MAX_NORM / fmaxf(tn, EPSV), 1.0f);

    float4 oa, ob;
    oa.x = a.x * scale; oa.y = a.y * scale; oa.z = a.z * scale; oa.w = a.w * scale;
    ob.x = b.x * scale; ob.y = b.y * scale; ob.z = b.z * scale; ob.w = b.w * scale;

    float4* o4 = (float4*)(ch + (size_t)row * D);
    o4[2 * lane]     = oa;
    o4[2 * lane + 1] = ob;

    union { ushort u[8]; uint4 v; } pk;
    pk.u[0] = f32_to_bf16(oa.x); pk.u[1] = f32_to_bf16(oa.y);
    pk.u[2] = f32_to_bf16(oa.z); pk.u[3] = f32_to_bf16(oa.w);
    pk.u[4] = f32_to_bf16(ob.x); pk.u[5] = f32_to_bf16(ob.y);
    pk.u[6] = f32_to_bf16(ob.z); pk.u[7] = f32_to_bf16(ob.w);
    ((uint4*)(cbf + (size_t)row * D))[lane] = pk.v;

    if (lane == 0) {
        const float sq = scale * scale * ss;
        y2raw[row] = sq;
        dyv[row]   = 1.0f - c * fminf(sq, MAX_NORM * MAX_NORM);
    }
}

// ---------------------------------------------------------------------------
// Kernel 3: bf16 MFMA GEMM + Poincare epilogue.
// 128x128 tile, BKT=64, single-buffered FRAGMENT-ORDER LDS (R4 loop, zero
// bank conflicts), plus LDS-TRANSPOSE EPILOGUE: raw xy acc -> per-wave LDS
// region -> read back row-major -> dist math -> float4-coalesced stores.
// ---------------------------------------------------------------------------
#define BM 128
#define BN 128
#define BKT 64
#define EPST 68   // epilogue LDS row stride in floats (16B-aligned rows, bank-skewed)

__global__ __launch_bounds__(256)
void gemm_epi_kernel(const ushort* __restrict__ Abf,   // M x K bf16
                     const ushort* __restrict__ Bbf,   // N x K bf16
                     const float* __restrict__ x2raw,
                     const float* __restrict__ dxv,
                     const float* __restrict__ y2raw,
                     const float* __restrict__ dyv,
                     const float* __restrict__ logc,
                     float* __restrict__ out,          // M x N
                     int M, int N, int K) {
    // 32 KB shared: K-loop uses it as As(16KB)+Bs(16KB); epilogue reuses it
    // as 4 per-wave transpose regions (16 rows x 68 floats = 4352 B each).
    __shared__ __align__(16) char smem[32768];
    ushort* As = (ushort*)smem;            // [16 subtiles][512]
    ushort* Bs = (ushort*)(smem + 16384);  // [16 subtiles][512]

    const int tid  = threadIdx.x;
    const int lane = tid & 63;
    const int wid  = tid >> 6;
    const int wm   = wid >> 1;     // 0..1
    const int wn   = wid & 1;      // 0..1

    const int bm = blockIdx.y;
    const int bn = blockIdx.x;

    const ushort* Ab = Abf + (size_t)bm * BM * K;
    const ushort* Bb = Bbf + (size_t)bn * BN * K;

    f32x4 acc[4][4];
#pragma unroll
    for (int m = 0; m < 4; m++)
#pragma unroll
        for (int n = 0; n < 4; n++) acc[m][n] = (f32x4){0.f, 0.f, 0.f, 0.f};

    // Per-lane fragment-order source offset within a 16x32 subtile:
    // row = lane&15, k = (lane>>4)*8
    const size_t fragoff = (size_t)(lane & 15) * K + ((lane >> 4) * 8);

    for (int k0 = 0; k0 < K; k0 += BKT) {
        // Wave w stages subtiles s = 4w..4w+3 (rowgroup rg = s>>1, khalf = s&1).
#pragma unroll
        for (int j = 0; j < 4; j++) {
            const int s  = wid * 4 + j;
            const int rg = s >> 1;
            const int kk = s & 1;
            const size_t goff = (size_t)(rg * 16) * K + k0 + kk * 32 + fragoff;
            glds16(Ab + goff, &As[s * 512]);
            glds16(Bb + goff, &Bs[s * 512]);
        }
        __syncthreads();

#pragma unroll
        for (int kk = 0; kk < 2; kk++) {
            short8 af[4], bfr[4];
#pragma unroll
            for (int m = 0; m < 4; m++)
                af[m] = *(const short8*)(&As[((wm * 4 + m) * 2 + kk) * 512 + lane * 8]);
#pragma unroll
            for (int n = 0; n < 4; n++)
                bfr[n] = *(const short8*)(&Bs[((wn * 4 + n) * 2 + kk) * 512 + lane * 8]);
#pragma unroll
            for (int m = 0; m < 4; m++)
#pragma unroll
                for (int n = 0; n < 4; n++)
                    acc[m][n] = __builtin_amdgcn_mfma_f32_16x16x32_bf16(
                        af[m], bfr[n], acc[m][n], 0, 0, 0);
        }
        __syncthreads();
    }

    // ---------------- Epilogue: LDS transpose + coalesced stores ------------
    // t = max(2c*diff2/denom, eps); dist = log(1+t+sqrt(t(t+2)))/sqrt(c)
    const float c   = expf(logc[0]);
    const float rsc = 1.0f / sqrtf(c);
    const int l16 = lane & 15;
    const int lg  = lane >> 4;

    float* ep = (float*)(smem + (size_t)wid * 4352);   // private [16][EPST]
    const int gr_base = bm * BM + wm * 64;
    const int gc_base = bn * BN + wn * 64;

#pragma unroll
    for (int m = 0; m < 4; m++) {
        // scatter this m-frag (16 rows x 64 cols) into the private region
#pragma unroll
        for (int n = 0; n < 4; n++)
#pragma unroll
            for (int r = 0; r < 4; r++)
                ep[(lg * 4 + r) * EPST + n * 16 + l16] = acc[m][n][r];
        asm volatile("s_waitcnt lgkmcnt(0)" ::: "memory");

        // read back row-major: 4 iters x (4 rows x 16 float4 chunks)
#pragma unroll
        for (int it = 0; it < 4; it++) {
            const int row = it * 4 + lg;                  // 0..15
            const int gr  = gr_base + m * 16 + row;
            const int gc  = gc_base + l16 * 4;
            float4 xy4 = *(const float4*)&ep[row * EPST + l16 * 4];
            const float rx  = x2raw[gr];
            const float dxr = dxv[gr];
            const float4 ry4 = *(const float4*)&y2raw[gc];
            const float4 dy4 = *(const float4*)&dyv[gc];
            float4 o;
            {
                const float rden = __builtin_amdgcn_rcpf(fmaxf(dxr * dy4.x, EPSV));
                float t = fmaxf(2.0f * c * (rx + ry4.x - 2.0f * xy4.x) * rden, EPSV);
                o.x = __logf(1.0f + t + __builtin_amdgcn_sqrtf(t * (t + 2.0f))) * rsc;
            }
            {
                const float rden = __builtin_amdgcn_rcpf(fmaxf(dxr * dy4.y, EPSV));
                float t = fmaxf(2.0f * c * (rx + ry4.y - 2.0f * xy4.y) * rden, EPSV);
                o.y = __logf(1.0f + t + __builtin_amdgcn_sqrtf(t * (t + 2.0f))) * rsc;
            }
            {
                const float rden = __builtin_amdgcn_rcpf(fmaxf(dxr * dy4.z, EPSV));
                float t = fmaxf(2.0f * c * (rx + ry4.z - 2.0f * xy4.z) * rden, EPSV);
                o.z = __logf(1.0f + t + __builtin_amdgcn_sqrtf(t * (t + 2.0f))) * rsc;
            }
            {
                const float rden = __builtin_amdgcn_rcpf(fmaxf(dxr * dy4.w, EPSV));
                float t = fmaxf(2.0f * c * (rx + ry4.w - 2.0f * xy4.w) * rden, EPSV);
                o.w = __logf(1.0f + t + __builtin_amdgcn_sqrtf(t * (t + 2.0f))) * rsc;
            }
            *(float4*)&out[(size_t)gr * N + gc] = o;
        }
        // region is reused next m-pass by the same wave only; ensure reads done
        asm volatile("s_waitcnt lgkmcnt(0)" ::: "memory");
    }
}

// ---------------------------------------------------------------------------
extern "C" void kernel_launch(void* const* d_in, const int* in_sizes, int n_in,
                              void* d_out, int out_size, void* d_ws, size_t ws_size,
                              hipStream_t stream) {
    const float* emb  = (const float*)d_in[0];   // (B, D) f32
    const float* logc = (const float*)d_in[1];   // scalar f32
    const float* cen  = (const float*)d_in[2];   // (C, D) f32

    const int D = 512;
    const int B = in_sizes[0] / D;   // 8192
    const int C = in_sizes[2] / D;   // 4096

    float* out   = (float*)d_out;
    float* dists = out;                          // B*C
    float* xh    = out + (size_t)B * C;          // B*D
    float* ch    = xh + (size_t)B * D;           // C*D

    char* ws = (char*)d_ws;
    size_t off = 0;
    auto alloc = [&](size_t bytes) -> char* {
        char* p = ws + off;
        off += (bytes + 255) & ~(size_t)255;
        return p;
    };
    ushort* xbf   = (ushort*)alloc((size_t)B * D * sizeof(ushort));
    ushort* cbf   = (ushort*)alloc((size_t)C * D * sizeof(ushort));
    float*  x2raw = (float*)alloc((size_t)B * sizeof(float));
    float*  dxv   = (float*)alloc((size_t)B * sizeof(float));
    float*  y2raw = (float*)alloc((size_t)C * sizeof(float));
    float*  dyv   = (float*)alloc((size_t)C * sizeof(float));

    rows_emb_kernel<<<B, 64, 0, stream>>>(emb, logc, xh, xbf, x2raw, dxv);
    rows_cen_kernel<<<C, 64, 0, stream>>>(cen, logc, ch, cbf, y2raw, dyv);

    dim3 grid(C / BN, B / BM);   // natural order: bn fastest (good XCD locality)
    gemm_epi_kernel<<<grid, 256, 0, stream>>>(xbf, cbf, x2raw, dxv, y2raw, dyv,
                                              logc, dists, B, C, D);
}

// Round 7
// 116.493 us; speedup vs baseline: 1.4924x; 1.0016x over previous
//
#include <hip/hip_runtime.h>
#include <math.h>

#define EPSV 1e-6f
#define MAX_NORM (1.0f - 1e-3f)

typedef __attribute__((ext_vector_type(8))) short short8;   // 8 bf16 = 4 VGPRs
typedef __attribute__((ext_vector_type(4))) float f32x4;    // MFMA acc

// f32 -> bf16 (round-to-nearest-even), returns raw 16-bit pattern
__device__ inline ushort f32_to_bf16(float f) {
    union { float f; uint32_t u; } cv;
    cv.f = f;
    uint32_t u = cv.u;
    u += 0x7FFFu + ((u >> 16) & 1u);
    return (ushort)(u >> 16);
}

// async global -> LDS, 16 bytes per lane (dest = uniform base + lane*16)
__device__ inline void glds16(const ushort* gsrc, ushort* ldsdst) {
    auto* g = (const __attribute__((address_space(1))) uint32_t*)gsrc;
    auto* l = (__attribute__((address_space(3))) uint32_t*)ldsdst;
    __builtin_amdgcn_global_load_lds(g, l, 16, 0, 0);
}

// ---------------------------------------------------------------------------
// Kernel 1: expmap0 + clip for embeddings. One wave (64 lanes) per row, D=512.
// ---------------------------------------------------------------------------
__global__ void rows_emb_kernel(const float* __restrict__ emb,
                                const float* __restrict__ logc,
                                float* __restrict__ xh,
                                ushort* __restrict__ xbf,
                                float* __restrict__ x2raw,
                                float* __restrict__ dxv) {
    const int D = 512;
    const int row = blockIdx.x;
    const int lane = threadIdx.x;   // 0..63

    const float4* r4 = (const float4*)(emb + (size_t)row * D);
    float4 a = r4[2 * lane];
    float4 b = r4[2 * lane + 1];

    float ss = a.x * a.x + a.y * a.y + a.z * a.z + a.w * a.w
             + b.x * b.x + b.y * b.y + b.z * b.z + b.w * b.w;
#pragma unroll
    for (int off = 32; off > 0; off >>= 1) ss += __shfl_xor(ss, off, 64);

    const float c  = expf(logc[0]);
    const float sc = sqrtf(c);

    const float tn    = sqrtf(ss);
    const float vn    = fmaxf(tn, EPSV);
    const float coeff = tanhf(sc * vn) / (sc * vn);
    const float pre   = coeff * tn;
    const float fac   = fminf(MAX_NORM / fmaxf(pre, EPSV), 1.0f);
    const float scale = coeff * fac;

    float4 oa, ob;
    oa.x = a.x * scale; oa.y = a.y * scale; oa.z = a.z * scale; oa.w = a.w * scale;
    ob.x = b.x * scale; ob.y = b.y * scale; ob.z = b.z * scale; ob.w = b.w * scale;

    float4* o4 = (float4*)(xh + (size_t)row * D);
    o4[2 * lane]     = oa;
    o4[2 * lane + 1] = ob;

    union { ushort u[8]; uint4 v; } pk;
    pk.u[0] = f32_to_bf16(oa.x); pk.u[1] = f32_to_bf16(oa.y);
    pk.u[2] = f32_to_bf16(oa.z); pk.u[3] = f32_to_bf16(oa.w);
    pk.u[4] = f32_to_bf16(ob.x); pk.u[5] = f32_to_bf16(ob.y);
    pk.u[6] = f32_to_bf16(ob.z); pk.u[7] = f32_to_bf16(ob.w);
    ((uint4*)(xbf + (size_t)row * D))[lane] = pk.v;

    if (lane == 0) {
        const float sq = scale * scale * ss;
        x2raw[row] = sq;
        dxv[row]   = 1.0f - c * fminf(sq, MAX_NORM * MAX_NORM);
    }
}

// ---------------------------------------------------------------------------
// Kernel 2: clip-only for centroids. One wave per row, D=512.
// ---------------------------------------------------------------------------
__global__ void rows_cen_kernel(const float* __restrict__ cen,
                                const float* __restrict__ logc,
                                float* __restrict__ ch,
                                ushort* __restrict__ cbf,
                                float* __restrict__ y2raw,
                                float* __restrict__ dyv) {
    const int D = 512;
    const int row = blockIdx.x;
    const int lane = threadIdx.x;

    const float4* r4 = (const float4*)(cen + (size_t)row * D);
    float4 a = r4[2 * lane];
    float4 b = r4[2 * lane + 1];

    float ss = a.x * a.x + a.y * a.y + a.z * a.z + a.w * a.w
             + b.x * b.x + b.y * b.y + b.z * b.z + b.w * b.w;
#pragma unroll
    for (int off = 32; off > 0; off >>= 1) ss += __shfl_xor(ss, off, 64);

    const float c = expf(logc[0]);

    const float tn    = sqrtf(ss);
    const float scale = fminf(MAX_NORM / fmaxf(tn, EPSV), 1.0f);

    float4 oa, ob;
    oa.x = a.x * scale; oa.y = a.y * scale; oa.z = a.z * scale; oa.w = a.w * scale;
    ob.x = b.x * scale; ob.y = b.y * scale; ob.z = b.z * scale; ob.w = b.w * scale;

    float4* o4 = (float4*)(ch + (size_t)row * D);
    o4[2 * lane]     = oa;
    o4[2 * lane + 1] = ob;

    union { ushort u[8]; uint4 v; } pk;
    pk.u[0] = f32_to_bf16(oa.x); pk.u[1] = f32_to_bf16(oa.y);
    pk.u[2] = f32_to_bf16(oa.z); pk.u[3] = f32_to_bf16(oa.w);
    pk.u[4] = f32_to_bf16(ob.x); pk.u[5] = f32_to_bf16(ob.y);
    pk.u[6] = f32_to_bf16(ob.z); pk.u[7] = f32_to_bf16(ob.w);
    ((uint4*)(cbf + (size_t)row * D))[lane] = pk.v;

    if (lane == 0) {
        const float sq = scale * scale * ss;
        y2raw[row] = sq;
        dyv[row]   = 1.0f - c * fminf(sq, MAX_NORM * MAX_NORM);
    }
}

// ---------------------------------------------------------------------------
// Kernel 3: bf16 MFMA GEMM + Poincare epilogue.
// 128x128 tile, BKT=64, single-buffered FRAGMENT-ORDER LDS (R4 loop, zero
// bank conflicts), plus LDS-TRANSPOSE EPILOGUE: raw xy acc -> per-wave LDS
// region -> read back row-major -> dist math -> float4-coalesced stores.
// ---------------------------------------------------------------------------
#define BM 128
#define BN 128
#define BKT 64
#define EPST 68   // epilogue LDS row stride in floats (16B-aligned rows, bank-skewed)

__global__ __launch_bounds__(256)
void gemm_epi_kernel(const ushort* __restrict__ Abf,   // M x K bf16
                     const ushort* __restrict__ Bbf,   // N x K bf16
                     const float* __restrict__ x2raw,
                     const float* __restrict__ dxv,
                     const float* __restrict__ y2raw,
                     const float* __restrict__ dyv,
                     const float* __restrict__ logc,
                     float* __restrict__ out,          // M x N
                     int M, int N, int K) {
    // 32 KB shared: K-loop uses it as As(16KB)+Bs(16KB); epilogue reuses it
    // as 4 per-wave transpose regions (16 rows x 68 floats = 4352 B each).
    __shared__ __align__(16) char smem[32768];
    ushort* As = (ushort*)smem;            // [16 subtiles][512]
    ushort* Bs = (ushort*)(smem + 16384);  // [16 subtiles][512]

    const int tid  = threadIdx.x;
    const int lane = tid & 63;
    const int wid  = tid >> 6;
    const int wm   = wid >> 1;     // 0..1
    const int wn   = wid & 1;      // 0..1

    const int bm = blockIdx.y;
    const int bn = blockIdx.x;

    const ushort* Ab = Abf + (size_t)bm * BM * K;
    const ushort* Bb = Bbf + (size_t)bn * BN * K;

    f32x4 acc[4][4];
#pragma unroll
    for (int m = 0; m < 4; m++)
#pragma unroll
        for (int n = 0; n < 4; n++) acc[m][n] = (f32x4){0.f, 0.f, 0.f, 0.f};

    // Per-lane fragment-order source offset within a 16x32 subtile:
    // row = lane&15, k = (lane>>4)*8
    const size_t fragoff = (size_t)(lane & 15) * K + ((lane >> 4) * 8);

    for (int k0 = 0; k0 < K; k0 += BKT) {
        // Wave w stages subtiles s = 4w..4w+3 (rowgroup rg = s>>1, khalf = s&1).
#pragma unroll
        for (int j = 0; j < 4; j++) {
            const int s  = wid * 4 + j;
            const int rg = s >> 1;
            const int kk = s & 1;
            const size_t goff = (size_t)(rg * 16) * K + k0 + kk * 32 + fragoff;
            glds16(Ab + goff, &As[s * 512]);
            glds16(Bb + goff, &Bs[s * 512]);
        }
        __syncthreads();

#pragma unroll
        for (int kk = 0; kk < 2; kk++) {
            short8 af[4], bfr[4];
#pragma unroll
            for (int m = 0; m < 4; m++)
                af[m] = *(const short8*)(&As[((wm * 4 + m) * 2 + kk) * 512 + lane * 8]);
#pragma unroll
            for (int n = 0; n < 4; n++)
                bfr[n] = *(const short8*)(&Bs[((wn * 4 + n) * 2 + kk) * 512 + lane * 8]);
#pragma unroll
            for (int m = 0; m < 4; m++)
#pragma unroll
                for (int n = 0; n < 4; n++)
                    acc[m][n] = __builtin_amdgcn_mfma_f32_16x16x32_bf16(
                        af[m], bfr[n], acc[m][n], 0, 0, 0);
        }
        __syncthreads();
    }

    // ---------------- Epilogue: LDS transpose + coalesced stores ------------
    // t = max(2c*diff2/denom, eps); dist = log(1+t+sqrt(t(t+2)))/sqrt(c)
    const float c   = expf(logc[0]);
    const float rsc = 1.0f / sqrtf(c);
    const int l16 = lane & 15;
    const int lg  = lane >> 4;

    float* ep = (float*)(smem + (size_t)wid * 4352);   // private [16][EPST]
    const int gr_base = bm * BM + wm * 64;
    const int gc_base = bn * BN + wn * 64;

#pragma unroll
    for (int m = 0; m < 4; m++) {
        // scatter this m-frag (16 rows x 64 cols) into the private region
#pragma unroll
        for (int n = 0; n < 4; n++)
#pragma unroll
            for (int r = 0; r < 4; r++)
                ep[(lg * 4 + r) * EPST + n * 16 + l16] = acc[m][n][r];
        asm volatile("s_waitcnt lgkmcnt(0)" ::: "memory");

        // read back row-major: 4 iters x (4 rows x 16 float4 chunks)
#pragma unroll
        for (int it = 0; it < 4; it++) {
            const int row = it * 4 + lg;                  // 0..15
            const int gr  = gr_base + m * 16 + row;
            const int gc  = gc_base + l16 * 4;
            float4 xy4 = *(const float4*)&ep[row * EPST + l16 * 4];
            const float rx  = x2raw[gr];
            const float dxr = dxv[gr];
            const float4 ry4 = *(const float4*)&y2raw[gc];
            const float4 dy4 = *(const float4*)&dyv[gc];
            float4 o;
            {
                const float rden = __builtin_amdgcn_rcpf(fmaxf(dxr * dy4.x, EPSV));
                float t = fmaxf(2.0f * c * (rx + ry4.x - 2.0f * xy4.x) * rden, EPSV);
                o.x = __logf(1.0f + t + __builtin_amdgcn_sqrtf(t * (t + 2.0f))) * rsc;
            }
            {
                const float rden = __builtin_amdgcn_rcpf(fmaxf(dxr * dy4.y, EPSV));
                float t = fmaxf(2.0f * c * (rx + ry4.y - 2.0f * xy4.y) * rden, EPSV);
                o.y = __logf(1.0f + t + __builtin_amdgcn_sqrtf(t * (t + 2.0f))) * rsc;
            }
            {
                const float rden = __builtin_amdgcn_rcpf(fmaxf(dxr * dy4.z, EPSV));
                float t = fmaxf(2.0f * c * (rx + ry4.z - 2.0f * xy4.z) * rden, EPSV);
                o.z = __logf(1.0f + t + __builtin_amdgcn_sqrtf(t * (t + 2.0f))) * rsc;
            }
            {
                const float rden = __builtin_amdgcn_rcpf(fmaxf(dxr * dy4.w, EPSV));
                float t = fmaxf(2.0f * c * (rx + ry4.w - 2.0f * xy4.w) * rden, EPSV);
                o.w = __logf(1.0f + t + __builtin_amdgcn_sqrtf(t * (t + 2.0f))) * rsc;
            }
            *(float4*)&out[(size_t)gr * N + gc] = o;
        }
        // region is reused next m-pass by the same wave only; ensure reads done
        asm volatile("s_waitcnt lgkmcnt(0)" ::: "memory");
    }
}

// ---------------------------------------------------------------------------
extern "C" void kernel_launch(void* const* d_in, const int* in_sizes, int n_in,
                              void* d_out, int out_size, void* d_ws, size_t ws_size,
                              hipStream_t stream) {
    const float* emb  = (const float*)d_in[0];   // (B, D) f32
    const float* logc = (const float*)d_in[1];   // scalar f32
    const float* cen  = (const float*)d_in[2];   // (C, D) f32

    const int D = 512;
    const int B = in_sizes[0] / D;   // 8192
    const int C = in_sizes[2] / D;   // 4096

    float* out   = (float*)d_out;
    float* dists = out;                          // B*C
    float* xh    = out + (size_t)B * C;          // B*D
    float* ch    = xh + (size_t)B * D;           // C*D

    char* ws = (char*)d_ws;
    size_t off = 0;
    auto alloc = [&](size_t bytes) -> char* {
        char* p = ws + off;
        off += (bytes + 255) & ~(size_t)255;
        return p;
    };
    ushort* xbf   = (ushort*)alloc((size_t)B * D * sizeof(ushort));
    ushort* cbf   = (ushort*)alloc((size_t)C * D * sizeof(ushort));
    float*  x2raw = (float*)alloc((size_t)B * sizeof(float));
    float*  dxv   = (float*)alloc((size_t)B * sizeof(float));
    float*  y2raw = (float*)alloc((size_t)C * sizeof(float));
    float*  dyv   = (float*)alloc((size_t)C * sizeof(float));

    rows_emb_kernel<<<B, 64, 0, stream>>>(emb, logc, xh, xbf, x2raw, dxv);
    rows_cen_kernel<<<C, 64, 0, stream>>>(cen, logc, ch, cbf, y2raw, dyv);

    dim3 grid(C / BN, B / BM);   // natural order: bn fastest (good XCD locality)
    gemm_epi_kernel<<<grid, 256, 0, stream>>>(xbf, cbf, x2raw, dxv, y2raw, dyv,
                                              logc, dists, B, C, D);
}

// Round 8
// 115.972 us; speedup vs baseline: 1.4991x; 1.0045x over previous
//
#include <hip/hip_runtime.h>
#include <math.h>

#define EPSV 1e-6f
#define MAX_NORM (1.0f - 1e-3f)

typedef __attribute__((ext_vector_type(8))) short short8;   // 8 bf16 = 4 VGPRs
typedef __attribute__((ext_vector_type(4))) float f32x4;    // MFMA acc

// f32 -> bf16 (round-to-nearest-even), returns raw 16-bit pattern
__device__ inline ushort f32_to_bf16(float f) {
    union { float f; uint32_t u; } cv;
    cv.f = f;
    uint32_t u = cv.u;
    u += 0x7FFFu + ((u >> 16) & 1u);
    return (ushort)(u >> 16);
}

// async global -> LDS, 16 bytes per lane (dest = uniform base + lane*16)
__device__ inline void glds16(const ushort* gsrc, ushort* ldsdst) {
    auto* g = (const __attribute__((address_space(1))) uint32_t*)gsrc;
    auto* l = (__attribute__((address_space(3))) uint32_t*)ldsdst;
    __builtin_amdgcn_global_load_lds(g, l, 16, 0, 0);
}

// ---------------------------------------------------------------------------
// Kernel 1: expmap0 + clip for embeddings. One wave (64 lanes) per row, D=512.
// ---------------------------------------------------------------------------
__global__ void rows_emb_kernel(const float* __restrict__ emb,
                                const float* __restrict__ logc,
                                float* __restrict__ xh,
                                ushort* __restrict__ xbf,
                                float* __restrict__ x2raw,
                                float* __restrict__ dxv) {
    const int D = 512;
    const int row = blockIdx.x;
    const int lane = threadIdx.x;   // 0..63

    const float4* r4 = (const float4*)(emb + (size_t)row * D);
    float4 a = r4[2 * lane];
    float4 b = r4[2 * lane + 1];

    float ss = a.x * a.x + a.y * a.y + a.z * a.z + a.w * a.w
             + b.x * b.x + b.y * b.y + b.z * b.z + b.w * b.w;
#pragma unroll
    for (int off = 32; off > 0; off >>= 1) ss += __shfl_xor(ss, off, 64);

    const float c  = expf(logc[0]);
    const float sc = sqrtf(c);

    const float tn    = sqrtf(ss);
    const float vn    = fmaxf(tn, EPSV);
    const float coeff = tanhf(sc * vn) / (sc * vn);
    const float pre   = coeff * tn;
    const float fac   = fminf(MAX_NORM / fmaxf(pre, EPSV), 1.0f);
    const float scale = coeff * fac;

    float4 oa, ob;
    oa.x = a.x * scale; oa.y = a.y * scale; oa.z = a.z * scale; oa.w = a.w * scale;
    ob.x = b.x * scale; ob.y = b.y * scale; ob.z = b.z * scale; ob.w = b.w * scale;

    float4* o4 = (float4*)(xh + (size_t)row * D);
    o4[2 * lane]     = oa;
    o4[2 * lane + 1] = ob;

    union { ushort u[8]; uint4 v; } pk;
    pk.u[0] = f32_to_bf16(oa.x); pk.u[1] = f32_to_bf16(oa.y);
    pk.u[2] = f32_to_bf16(oa.z); pk.u[3] = f32_to_bf16(oa.w);
    pk.u[4] = f32_to_bf16(ob.x); pk.u[5] = f32_to_bf16(ob.y);
    pk.u[6] = f32_to_bf16(ob.z); pk.u[7] = f32_to_bf16(ob.w);
    ((uint4*)(xbf + (size_t)row * D))[lane] = pk.v;

    if (lane == 0) {
        const float sq = scale * scale * ss;
        x2raw[row] = sq;
        dxv[row]   = 1.0f - c * fminf(sq, MAX_NORM * MAX_NORM);
    }
}

// ---------------------------------------------------------------------------
// Kernel 2: clip-only for centroids. One wave per row, D=512.
// ---------------------------------------------------------------------------
__global__ void rows_cen_kernel(const float* __restrict__ cen,
                                const float* __restrict__ logc,
                                float* __restrict__ ch,
                                ushort* __restrict__ cbf,
                                float* __restrict__ y2raw,
                                float* __restrict__ dyv) {
    const int D = 512;
    const int row = blockIdx.x;
    const int lane = threadIdx.x;

    const float4* r4 = (const float4*)(cen + (size_t)row * D);
    float4 a = r4[2 * lane];
    float4 b = r4[2 * lane + 1];

    float ss = a.x * a.x + a.y * a.y + a.z * a.z + a.w * a.w
             + b.x * b.x + b.y * b.y + b.z * b.z + b.w * b.w;
#pragma unroll
    for (int off = 32; off > 0; off >>= 1) ss += __shfl_xor(ss, off, 64);

    const float c = expf(logc[0]);

    const float tn    = sqrtf(ss);
    const float scale = fminf(MAX_NORM / fmaxf(tn, EPSV), 1.0f);

    float4 oa, ob;
    oa.x = a.x * scale; oa.y = a.y * scale; oa.z = a.z * scale; oa.w = a.w * scale;
    ob.x = b.x * scale; ob.y = b.y * scale; ob.z = b.z * scale; ob.w = b.w * scale;

    float4* o4 = (float4*)(ch + (size_t)row * D);
    o4[2 * lane]     = oa;
    o4[2 * lane + 1] = ob;

    union { ushort u[8]; uint4 v; } pk;
    pk.u[0] = f32_to_bf16(oa.x); pk.u[1] = f32_to_bf16(oa.y);
    pk.u[2] = f32_to_bf16(oa.z); pk.u[3] = f32_to_bf16(oa.w);
    pk.u[4] = f32_to_bf16(ob.x); pk.u[5] = f32_to_bf16(ob.y);
    pk.u[6] = f32_to_bf16(ob.z); pk.u[7] = f32_to_bf16(ob.w);
    ((uint4*)(cbf + (size_t)row * D))[lane] = pk.v;

    if (lane == 0) {
        const float sq = scale * scale * ss;
        y2raw[row] = sq;
        dyv[row]   = 1.0f - c * fminf(sq, MAX_NORM * MAX_NORM);
    }
}

// ---------------------------------------------------------------------------
// Kernel 3: bf16 MFMA GEMM + Poincare epilogue.
// 128x128 tile, BKT=64, single-buffered FRAGMENT-ORDER LDS (R4 loop, zero
// bank conflicts), plus LDS-TRANSPOSE EPILOGUE: raw xy acc -> per-wave LDS
// region -> read back row-major -> dist math -> float4-coalesced stores.
// ---------------------------------------------------------------------------
#define BM 128
#define BN 128
#define BKT 64
#define EPST 68   // epilogue LDS row stride in floats (16B-aligned rows, bank-skewed)

__global__ __launch_bounds__(256)
void gemm_epi_kernel(const ushort* __restrict__ Abf,   // M x K bf16
                     const ushort* __restrict__ Bbf,   // N x K bf16
                     const float* __restrict__ x2raw,
                     const float* __restrict__ dxv,
                     const float* __restrict__ y2raw,
                     const float* __restrict__ dyv,
                     const float* __restrict__ logc,
                     float* __restrict__ out,          // M x N
                     int M, int N, int K) {
    // 32 KB shared: K-loop uses it as As(16KB)+Bs(16KB); epilogue reuses it
    // as 4 per-wave transpose regions (16 rows x 68 floats = 4352 B each).
    __shared__ __align__(16) char smem[32768];
    ushort* As = (ushort*)smem;            // [16 subtiles][512]
    ushort* Bs = (ushort*)(smem + 16384);  // [16 subtiles][512]

    const int tid  = threadIdx.x;
    const int lane = tid & 63;
    const int wid  = tid >> 6;
    const int wm   = wid >> 1;     // 0..1
    const int wn   = wid & 1;      // 0..1

    const int bm = blockIdx.y;
    const int bn = blockIdx.x;

    const ushort* Ab = Abf + (size_t)bm * BM * K;
    const ushort* Bb = Bbf + (size_t)bn * BN * K;

    f32x4 acc[4][4];
#pragma unroll
    for (int m = 0; m < 4; m++)
#pragma unroll
        for (int n = 0; n < 4; n++) acc[m][n] = (f32x4){0.f, 0.f, 0.f, 0.f};

    // Per-lane fragment-order source offset within a 16x32 subtile:
    // row = lane&15, k = (lane>>4)*8
    const size_t fragoff = (size_t)(lane & 15) * K + ((lane >> 4) * 8);

    for (int k0 = 0; k0 < K; k0 += BKT) {
        // Wave w stages subtiles s = 4w..4w+3 (rowgroup rg = s>>1, khalf = s&1).
#pragma unroll
        for (int j = 0; j < 4; j++) {
            const int s  = wid * 4 + j;
            const int rg = s >> 1;
            const int kk = s & 1;
            const size_t goff = (size_t)(rg * 16) * K + k0 + kk * 32 + fragoff;
            glds16(Ab + goff, &As[s * 512]);
            glds16(Bb + goff, &Bs[s * 512]);
        }
        __syncthreads();

#pragma unroll
        for (int kk = 0; kk < 2; kk++) {
            short8 af[4], bfr[4];
#pragma unroll
            for (int m = 0; m < 4; m++)
                af[m] = *(const short8*)(&As[((wm * 4 + m) * 2 + kk) * 512 + lane * 8]);
#pragma unroll
            for (int n = 0; n < 4; n++)
                bfr[n] = *(const short8*)(&Bs[((wn * 4 + n) * 2 + kk) * 512 + lane * 8]);
#pragma unroll
            for (int m = 0; m < 4; m++)
#pragma unroll
                for (int n = 0; n < 4; n++)
                    acc[m][n] = __builtin_amdgcn_mfma_f32_16x16x32_bf16(
                        af[m], bfr[n], acc[m][n], 0, 0, 0);
        }
        __syncthreads();
    }

    // ---------------- Epilogue: LDS transpose + coalesced stores ------------
    // t = max(2c*diff2/denom, eps); dist = log(1+t+sqrt(t(t+2)))/sqrt(c)
    const float c   = expf(logc[0]);
    const float rsc = 1.0f / sqrtf(c);
    const int l16 = lane & 15;
    const int lg  = lane >> 4;

    float* ep = (float*)(smem + (size_t)wid * 4352);   // private [16][EPST]
    const int gr_base = bm * BM + wm * 64;
    const int gc_base = bn * BN + wn * 64;

#pragma unroll
    for (int m = 0; m < 4; m++) {
        // scatter this m-frag (16 rows x 64 cols) into the private region
#pragma unroll
        for (int n = 0; n < 4; n++)
#pragma unroll
            for (int r = 0; r < 4; r++)
                ep[(lg * 4 + r) * EPST + n * 16 + l16] = acc[m][n][r];
        asm volatile("s_waitcnt lgkmcnt(0)" ::: "memory");

        // read back row-major: 4 iters x (4 rows x 16 float4 chunks)
#pragma unroll
        for (int it = 0; it < 4; it++) {
            const int row = it * 4 + lg;                  // 0..15
            const int gr  = gr_base + m * 16 + row;
            const int gc  = gc_base + l16 * 4;
            float4 xy4 = *(const float4*)&ep[row * EPST + l16 * 4];
            const float rx  = x2raw[gr];
            const float dxr = dxv[gr];
            const float4 ry4 = *(const float4*)&y2raw[gc];
            const float4 dy4 = *(const float4*)&dyv[gc];
            float4 o;
            {
                const float rden = __builtin_amdgcn_rcpf(fmaxf(dxr * dy4.x, EPSV));
                float t = fmaxf(2.0f * c * (rx + ry4.x - 2.0f * xy4.x) * rden, EPSV);
                o.x = __logf(1.0f + t + __builtin_amdgcn_sqrtf(t * (t + 2.0f))) * rsc;
            }
            {
                const float rden = __builtin_amdgcn_rcpf(fmaxf(dxr * dy4.y, EPSV));
                float t = fmaxf(2.0f * c * (rx + ry4.y - 2.0f * xy4.y) * rden, EPSV);
                o.y = __logf(1.0f + t + __builtin_amdgcn_sqrtf(t * (t + 2.0f))) * rsc;
            }
            {
                const float rden = __builtin_amdgcn_rcpf(fmaxf(dxr * dy4.z, EPSV));
                float t = fmaxf(2.0f * c * (rx + ry4.z - 2.0f * xy4.z) * rden, EPSV);
                o.z = __logf(1.0f + t + __builtin_amdgcn_sqrtf(t * (t + 2.0f))) * rsc;
            }
            {
                const float rden = __builtin_amdgcn_rcpf(fmaxf(dxr * dy4.w, EPSV));
                float t = fmaxf(2.0f * c * (rx + ry4.w - 2.0f * xy4.w) * rden, EPSV);
                o.w = __logf(1.0f + t + __builtin_amdgcn_sqrtf(t * (t + 2.0f))) * rsc;
            }
            *(float4*)&out[(size_t)gr * N + gc] = o;
        }
        // region is reused next m-pass by the same wave only; ensure reads done
        asm volatile("s_waitcnt lgkmcnt(0)" ::: "memory");
    }
}

// ---------------------------------------------------------------------------
extern "C" void kernel_launch(void* const* d_in, const int* in_sizes, int n_in,
                              void* d_out, int out_size, void* d_ws, size_t ws_size,
                              hipStream_t stream) {
    const float* emb  = (const float*)d_in[0];   // (B, D) f32
    const float* logc = (const float*)d_in[1];   // scalar f32
    const float* cen  = (const float*)d_in[2];   // (C, D) f32

    const int D = 512;
    const int B = in_sizes[0] / D;   // 8192
    const int C = in_sizes[2] / D;   // 4096

    float* out   = (float*)d_out;
    float* dists = out;                          // B*C
    float* xh    = out + (size_t)B * C;          // B*D
    float* ch    = xh + (size_t)B * D;           // C*D

    char* ws = (char*)d_ws;
    size_t off = 0;
    auto alloc = [&](size_t bytes) -> char* {
        char* p = ws + off;
        off += (bytes + 255) & ~(size_t)255;
        return p;
    };
    ushort* xbf   = (ushort*)alloc((size_t)B * D * sizeof(ushort));
    ushort* cbf   = (ushort*)alloc((size_t)C * D * sizeof(ushort));
    float*  x2raw = (float*)alloc((size_t)B * sizeof(float));
    float*  dxv   = (float*)alloc((size_t)B * sizeof(float));
    float*  y2raw = (float*)alloc((size_t)C * sizeof(float));
    float*  dyv   = (float*)alloc((size_t)C * sizeof(float));

    rows_emb_kernel<<<B, 64, 0, stream>>>(emb, logc, xh, xbf, x2raw, dxv);
    rows_cen_kernel<<<C, 64, 0, stream>>>(cen, logc, ch, cbf, y2raw, dyv);

    dim3 grid(C / BN, B / BM);   // natural order: bn fastest (good XCD locality)
    gemm_epi_kernel<<<grid, 256, 0, stream>>>(xbf, cbf, x2raw, dxv, y2raw, dyv,
                                              logc, dists, B, C, D);
}

// Round 9
// 99.916 us; speedup vs baseline: 1.7400x; 1.1607x over previous
//
#include <hip/hip_runtime.h>
#include <math.h>

#define EPSV 1e-6f
#define MAX_NORM (1.0f - 1e-3f)

typedef __attribute__((ext_vector_type(8))) short short8;   // 8 bf16 = 4 VGPRs
typedef __attribute__((ext_vector_type(4))) float f32x4;    // MFMA acc

// f32 -> bf16 (round-to-nearest-even), returns raw 16-bit pattern
__device__ inline ushort f32_to_bf16(float f) {
    union { float f; uint32_t u; } cv;
    cv.f = f;
    uint32_t u = cv.u;
    u += 0x7FFFu + ((u >> 16) & 1u);
    return (ushort)(u >> 16);
}

// async global -> LDS, 16 bytes per lane (dest = uniform base + lane*16)
__device__ inline void glds16(const ushort* gsrc, ushort* ldsdst) {
    auto* g = (const __attribute__((address_space(1))) uint32_t*)gsrc;
    auto* l = (__attribute__((address_space(3))) uint32_t*)ldsdst;
    __builtin_amdgcn_global_load_lds(g, l, 16, 0, 0);
}

// ---------------------------------------------------------------------------
// Kernel 1: expmap0 + clip for embeddings. One wave (64 lanes) per row, D=512.
// ---------------------------------------------------------------------------
__global__ void rows_emb_kernel(const float* __restrict__ emb,
                                const float* __restrict__ logc,
                                float* __restrict__ xh,
                                ushort* __restrict__ xbf,
                                float* __restrict__ x2raw,
                                float* __restrict__ dxv) {
    const int D = 512;
    const int row = blockIdx.x;
    const int lane = threadIdx.x;   // 0..63

    const float4* r4 = (const float4*)(emb + (size_t)row * D);
    float4 a = r4[2 * lane];
    float4 b = r4[2 * lane + 1];

    float ss = a.x * a.x + a.y * a.y + a.z * a.z + a.w * a.w
             + b.x * b.x + b.y * b.y + b.z * b.z + b.w * b.w;
#pragma unroll
    for (int off = 32; off > 0; off >>= 1) ss += __shfl_xor(ss, off, 64);

    const float c  = expf(logc[0]);
    const float sc = sqrtf(c);

    const float tn    = sqrtf(ss);
    const float vn    = fmaxf(tn, EPSV);
    const float coeff = tanhf(sc * vn) / (sc * vn);
    const float pre   = coeff * tn;
    const float fac   = fminf(MAX_NORM / fmaxf(pre, EPSV), 1.0f);
    const float scale = coeff * fac;

    float4 oa, ob;
    oa.x = a.x * scale; oa.y = a.y * scale; oa.z = a.z * scale; oa.w = a.w * scale;
    ob.x = b.x * scale; ob.y = b.y * scale; ob.z = b.z * scale; ob.w = b.w * scale;

    float4* o4 = (float4*)(xh + (size_t)row * D);
    o4[2 * lane]     = oa;
    o4[2 * lane + 1] = ob;

    union { ushort u[8]; uint4 v; } pk;
    pk.u[0] = f32_to_bf16(oa.x); pk.u[1] = f32_to_bf16(oa.y);
    pk.u[2] = f32_to_bf16(oa.z); pk.u[3] = f32_to_bf16(oa.w);
    pk.u[4] = f32_to_bf16(ob.x); pk.u[5] = f32_to_bf16(ob.y);
    pk.u[6] = f32_to_bf16(ob.z); pk.u[7] = f32_to_bf16(ob.w);
    ((uint4*)(xbf + (size_t)row * D))[lane] = pk.v;

    if (lane == 0) {
        const float sq = scale * scale * ss;
        x2raw[row] = sq;
        dxv[row]   = 1.0f - c * fminf(sq, MAX_NORM * MAX_NORM);
    }
}

// ---------------------------------------------------------------------------
// Kernel 2: clip-only for centroids. One wave per row, D=512.
// ---------------------------------------------------------------------------
__global__ void rows_cen_kernel(const float* __restrict__ cen,
                                const float* __restrict__ logc,
                                float* __restrict__ ch,
                                ushort* __restrict__ cbf,
                                float* __restrict__ y2raw,
                                float* __restrict__ dyv) {
    const int D = 512;
    const int row = blockIdx.x;
    const int lane = threadIdx.x;

    const float4* r4 = (const float4*)(cen + (size_t)row * D);
    float4 a = r4[2 * lane];
    float4 b = r4[2 * lane + 1];

    float ss = a.x * a.x + a.y * a.y + a.z * a.z + a.w * a.w
             + b.x * b.x + b.y * b.y + b.z * b.z + b.w * b.w;
#pragma unroll
    for (int off = 32; off > 0; off >>= 1) ss += __shfl_xor(ss, off, 64);

    const float c = expf(logc[0]);

    const float tn    = sqrtf(ss);
    const float scale = fminf(MAX_NORM / fmaxf(tn, EPSV), 1.0f);

    float4 oa, ob;
    oa.x = a.x * scale; oa.y = a.y * scale; oa.z = a.z * scale; oa.w = a.w * scale;
    ob.x = b.x * scale; ob.y = b.y * scale; ob.z = b.z * scale; ob.w = b.w * scale;

    float4* o4 = (float4*)(ch + (size_t)row * D);
    o4[2 * lane]     = oa;
    o4[2 * lane + 1] = ob;

    union { ushort u[8]; uint4 v; } pk;
    pk.u[0] = f32_to_bf16(oa.x); pk.u[1] = f32_to_bf16(oa.y);
    pk.u[2] = f32_to_bf16(oa.z); pk.u[3] = f32_to_bf16(oa.w);
    pk.u[4] = f32_to_bf16(ob.x); pk.u[5] = f32_to_bf16(ob.y);
    pk.u[6] = f32_to_bf16(ob.z); pk.u[7] = f32_to_bf16(ob.w);
    ((uint4*)(cbf + (size_t)row * D))[lane] = pk.v;

    if (lane == 0) {
        const float sq = scale * scale * ss;
        y2raw[row] = sq;
        dyv[row]   = 1.0f - c * fminf(sq, MAX_NORM * MAX_NORM);
    }
}

// ---------------------------------------------------------------------------
// Kernel 3: bf16 MFMA GEMM + Poincare epilogue.
// 256x256 tile, BK=64, 8 waves (2Mx4N, each 128x64 = 8x4 frags of
// mfma_f32_16x16x32_bf16). DOUBLE-BUFFERED fragment-order LDS (128 KB),
// catalog-minimal 2-phase loop: stage(next) BEFORE ds_read+MFMA(cur), one
// __syncthreads() (vmcnt0+barrier) per K-tile — the ~2048cy MFMA phase per
// SIMD covers the load latency, so the drain is ~free (unlike 128^2 where
// the 512cy MFMA phase < 900cy latency; R5's neutral result).
// Epilogue: per-wave LDS transpose (aliases staging LDS) + float4 stores.
// ---------------------------------------------------------------------------
#define BM 256
#define BN 256
#define BKT 64
#define EPST 68   // epilogue LDS row stride in floats

__global__ __launch_bounds__(512, 2)
void gemm_epi_kernel(const ushort* __restrict__ Abf,   // M x K bf16
                     const ushort* __restrict__ Bbf,   // N x K bf16
                     const float* __restrict__ x2raw,
                     const float* __restrict__ dxv,
                     const float* __restrict__ y2raw,
                     const float* __restrict__ dyv,
                     const float* __restrict__ logc,
                     float* __restrict__ out,          // M x N
                     int M, int N, int K) {
    // 128 KB: two buffers x (A 32 subtiles + B 32 subtiles) x 1KB.
    // Subtile s of buffer p: rowgroup rg = s>>1 (16 rows), khalf = s&1 (32 k),
    // stored in exact MFMA fragment order (lane l -> row l&15, k (l>>4)*8).
    __shared__ __align__(16) ushort As[2][32 * 512];
    __shared__ __align__(16) ushort Bs[2][32 * 512];

    const int tid  = threadIdx.x;
    const int lane = tid & 63;
    const int wid  = tid >> 6;     // 0..7
    const int wm   = wid >> 2;     // 0..1  (128-row half)
    const int wn   = wid & 3;      // 0..3  (64-col quarter)

    const int bm = blockIdx.y;
    const int bn = blockIdx.x;

    const ushort* Ab = Abf + (size_t)bm * BM * K;
    const ushort* Bb = Bbf + (size_t)bn * BN * K;

    f32x4 acc[8][4];
#pragma unroll
    for (int m = 0; m < 8; m++)
#pragma unroll
        for (int n = 0; n < 4; n++) acc[m][n] = (f32x4){0.f, 0.f, 0.f, 0.f};

    // Per-lane fragment-order source offset within a 16x32 subtile.
    const size_t fragoff = (size_t)(lane & 15) * K + ((lane >> 4) * 8);

    // Stage one K-tile (64 KB) into buffer p: wave w covers subtiles 4w..4w+3
    // of both A and B (8 glds16 calls/wave).
    auto stage = [&](int p, int k0) {
#pragma unroll
        for (int j = 0; j < 4; j++) {
            const int s  = wid * 4 + j;
            const int rg = s >> 1;
            const int kk = s & 1;
            const size_t goff = (size_t)(rg * 16) * K + k0 + kk * 32 + fragoff;
            glds16(Ab + goff, &As[p][s * 512]);
            glds16(Bb + goff, &Bs[p][s * 512]);
        }
    };

    stage(0, 0);
    __syncthreads();                 // drain prologue loads

    const int NT = K / BKT;          // 8
    int p = 0;
    for (int t = 0; t < NT; t++) {
        if (t + 1 < NT) stage(p ^ 1, (t + 1) * BKT);   // issue next-tile loads

#pragma unroll
        for (int kk = 0; kk < 2; kk++) {
            short8 af[8], bfr[4];
#pragma unroll
            for (int m = 0; m < 8; m++)
                af[m] = *(const short8*)(&As[p][((wm * 8 + m) * 2 + kk) * 512 + lane * 8]);
#pragma unroll
            for (int n = 0; n < 4; n++)
                bfr[n] = *(const short8*)(&Bs[p][((wn * 4 + n) * 2 + kk) * 512 + lane * 8]);
#pragma unroll
            for (int m = 0; m < 8; m++)
#pragma unroll
                for (int n = 0; n < 4; n++)
                    acc[m][n] = __builtin_amdgcn_mfma_f32_16x16x32_bf16(
                        af[m], bfr[n], acc[m][n], 0, 0, 0);
        }

        if (t + 1 < NT) __syncthreads();   // vmcnt0+barrier: prefetch landed
        p ^= 1;
    }

    __syncthreads();   // all waves done with staging LDS before epilogue reuse

    // ---------------- Epilogue: LDS transpose + coalesced stores ------------
    const float c   = expf(logc[0]);
    const float rsc = 1.0f / sqrtf(c);
    const int l16 = lane & 15;
    const int lg  = lane >> 4;

    float* ep = (float*)((char*)As + (size_t)wid * 4352);  // private [16][EPST]
    const int gr_base = bm * BM + wm * 128;
    const int gc_base = bn * BN + wn * 64;

#pragma unroll
    for (int m = 0; m < 8; m++) {
        // scatter this m-frag (16 rows x 64 cols) into the private region
#pragma unroll
        for (int n = 0; n < 4; n++)
#pragma unroll
            for (int r = 0; r < 4; r++)
                ep[(lg * 4 + r) * EPST + n * 16 + l16] = acc[m][n][r];
        asm volatile("s_waitcnt lgkmcnt(0)" ::: "memory");

        // read back row-major: 4 iters x (4 rows x 16 float4 chunks)
#pragma unroll
        for (int it = 0; it < 4; it++) {
            const int row = it * 4 + lg;                  // 0..15
            const int gr  = gr_base + m * 16 + row;
            const int gc  = gc_base + l16 * 4;
            float4 xy4 = *(const float4*)&ep[row * EPST + l16 * 4];
            const float rx  = x2raw[gr];
            const float dxr = dxv[gr];
            const float4 ry4 = *(const float4*)&y2raw[gc];
            const float4 dy4 = *(const float4*)&dyv[gc];
            float4 o;
            {
                const float rden = __builtin_amdgcn_rcpf(fmaxf(dxr * dy4.x, EPSV));
                float t = fmaxf(2.0f * c * (rx + ry4.x - 2.0f * xy4.x) * rden, EPSV);
                o.x = __logf(1.0f + t + __builtin_amdgcn_sqrtf(t * (t + 2.0f))) * rsc;
            }
            {
                const float rden = __builtin_amdgcn_rcpf(fmaxf(dxr * dy4.y, EPSV));
                float t = fmaxf(2.0f * c * (rx + ry4.y - 2.0f * xy4.y) * rden, EPSV);
                o.y = __logf(1.0f + t + __builtin_amdgcn_sqrtf(t * (t + 2.0f))) * rsc;
            }
            {
                const float rden = __builtin_amdgcn_rcpf(fmaxf(dxr * dy4.z, EPSV));
                float t = fmaxf(2.0f * c * (rx + ry4.z - 2.0f * xy4.z) * rden, EPSV);
                o.z = __logf(1.0f + t + __builtin_amdgcn_sqrtf(t * (t + 2.0f))) * rsc;
            }
            {
                const float rden = __builtin_amdgcn_rcpf(fmaxf(dxr * dy4.w, EPSV));
                float t = fmaxf(2.0f * c * (rx + ry4.w - 2.0f * xy4.w) * rden, EPSV);
                o.w = __logf(1.0f + t + __builtin_amdgcn_sqrtf(t * (t + 2.0f))) * rsc;
            }
            *(float4*)&out[(size_t)gr * N + gc] = o;
        }
        asm volatile("s_waitcnt lgkmcnt(0)" ::: "memory");
    }
}

// ---------------------------------------------------------------------------
extern "C" void kernel_launch(void* const* d_in, const int* in_sizes, int n_in,
                              void* d_out, int out_size, void* d_ws, size_t ws_size,
                              hipStream_t stream) {
    const float* emb  = (const float*)d_in[0];   // (B, D) f32
    const float* logc = (const float*)d_in[1];   // scalar f32
    const float* cen  = (const float*)d_in[2];   // (C, D) f32

    const int D = 512;
    const int B = in_sizes[0] / D;   // 8192
    const int C = in_sizes[2] / D;   // 4096

    float* out   = (float*)d_out;
    float* dists = out;                          // B*C
    float* xh    = out + (size_t)B * C;          // B*D
    float* ch    = xh + (size_t)B * D;           // C*D

    char* ws = (char*)d_ws;
    size_t off = 0;
    auto alloc = [&](size_t bytes) -> char* {
        char* p = ws + off;
        off += (bytes + 255) & ~(size_t)255;
        return p;
    };
    ushort* xbf   = (ushort*)alloc((size_t)B * D * sizeof(ushort));
    ushort* cbf   = (ushort*)alloc((size_t)C * D * sizeof(ushort));
    float*  x2raw = (float*)alloc((size_t)B * sizeof(float));
    float*  dxv   = (float*)alloc((size_t)B * sizeof(float));
    float*  y2raw = (float*)alloc((size_t)C * sizeof(float));
    float*  dyv   = (float*)alloc((size_t)C * sizeof(float));

    rows_emb_kernel<<<B, 64, 0, stream>>>(emb, logc, xh, xbf, x2raw, dxv);
    rows_cen_kernel<<<C, 64, 0, stream>>>(cen, logc, ch, cbf, y2raw, dyv);

    dim3 grid(C / BN, B / BM);   // (16, 32)
    gemm_epi_kernel<<<grid, 512, 0, stream>>>(xbf, cbf, x2raw, dxv, y2raw, dyv,
                                              logc, dists, B, C, D);
}

// Round 10
// 93.570 us; speedup vs baseline: 1.8580x; 1.0678x over previous
//
#include <hip/hip_runtime.h>
#include <math.h>

#define EPSV 1e-6f
#define MAX_NORM (1.0f - 1e-3f)

typedef __attribute__((ext_vector_type(8))) short short8;   // 8 bf16 = 4 VGPRs
typedef __attribute__((ext_vector_type(4))) float f32x4;    // MFMA acc

// f32 -> bf16 (round-to-nearest-even), returns raw 16-bit pattern
__device__ inline ushort f32_to_bf16(float f) {
    union { float f; uint32_t u; } cv;
    cv.f = f;
    uint32_t u = cv.u;
    u += 0x7FFFu + ((u >> 16) & 1u);
    return (ushort)(u >> 16);
}

// async global -> LDS, 16 bytes per lane (dest = uniform base + lane*16)
__device__ inline void glds16(const ushort* gsrc, ushort* ldsdst) {
    auto* g = (const __attribute__((address_space(1))) uint32_t*)gsrc;
    auto* l = (__attribute__((address_space(3))) uint32_t*)ldsdst;
    __builtin_amdgcn_global_load_lds(g, l, 16, 0, 0);
}

// inline-asm ds_read_b128: opaque to compiler alias analysis (no auto vmcnt)
__device__ inline short8 ds_read128(const ushort* p) {
    auto* l3 = (const __attribute__((address_space(3))) ushort*)p;
    const uint32_t addr = (uint32_t)(uintptr_t)l3;
    short8 v;
    asm volatile("ds_read_b128 %0, %1" : "=&v"(v) : "v"(addr));
    return v;
}

// ---------------------------------------------------------------------------
// Kernel 1: expmap0 + clip for embeddings. One wave (64 lanes) per row, D=512.
// ---------------------------------------------------------------------------
__global__ void rows_emb_kernel(const float* __restrict__ emb,
                                const float* __restrict__ logc,
                                float* __restrict__ xh,
                                ushort* __restrict__ xbf,
                                float* __restrict__ x2raw,
                                float* __restrict__ dxv) {
    const int D = 512;
    const int row = blockIdx.x;
    const int lane = threadIdx.x;   // 0..63

    const float4* r4 = (const float4*)(emb + (size_t)row * D);
    float4 a = r4[2 * lane];
    float4 b = r4[2 * lane + 1];

    float ss = a.x * a.x + a.y * a.y + a.z * a.z + a.w * a.w
             + b.x * b.x + b.y * b.y + b.z * b.z + b.w * b.w;
#pragma unroll
    for (int off = 32; off > 0; off >>= 1) ss += __shfl_xor(ss, off, 64);

    const float c  = expf(logc[0]);
    const float sc = sqrtf(c);

    const float tn    = sqrtf(ss);
    const float vn    = fmaxf(tn, EPSV);
    const float coeff = tanhf(sc * vn) / (sc * vn);
    const float pre   = coeff * tn;
    const float fac   = fminf(MAX_NORM / fmaxf(pre, EPSV), 1.0f);
    const float scale = coeff * fac;

    float4 oa, ob;
    oa.x = a.x * scale; oa.y = a.y * scale; oa.z = a.z * scale; oa.w = a.w * scale;
    ob.x = b.x * scale; ob.y = b.y * scale; ob.z = b.z * scale; ob.w = b.w * scale;

    float4* o4 = (float4*)(xh + (size_t)row * D);
    o4[2 * lane]     = oa;
    o4[2 * lane + 1] = ob;

    union { ushort u[8]; uint4 v; } pk;
    pk.u[0] = f32_to_bf16(oa.x); pk.u[1] = f32_to_bf16(oa.y);
    pk.u[2] = f32_to_bf16(oa.z); pk.u[3] = f32_to_bf16(oa.w);
    pk.u[4] = f32_to_bf16(ob.x); pk.u[5] = f32_to_bf16(ob.y);
    pk.u[6] = f32_to_bf16(ob.z); pk.u[7] = f32_to_bf16(ob.w);
    ((uint4*)(xbf + (size_t)row * D))[lane] = pk.v;

    if (lane == 0) {
        const float sq = scale * scale * ss;
        x2raw[row] = sq;
        dxv[row]   = 1.0f - c * fminf(sq, MAX_NORM * MAX_NORM);
    }
}

// ---------------------------------------------------------------------------
// Kernel 2: clip-only for centroids. One wave per row, D=512.
// ---------------------------------------------------------------------------
__global__ void rows_cen_kernel(const float* __restrict__ cen,
                                const float* __restrict__ logc,
                                float* __restrict__ ch,
                                ushort* __restrict__ cbf,
                                float* __restrict__ y2raw,
                                float* __restrict__ dyv) {
    const int D = 512;
    const int row = blockIdx.x;
    const int lane = threadIdx.x;

    const float4* r4 = (const float4*)(cen + (size_t)row * D);
    float4 a = r4[2 * lane];
    float4 b = r4[2 * lane + 1];

    float ss = a.x * a.x + a.y * a.y + a.z * a.z + a.w * a.w
             + b.x * b.x + b.y * b.y + b.z * b.z + b.w * b.w;
#pragma unroll
    for (int off = 32; off > 0; off >>= 1) ss += __shfl_xor(ss, off, 64);

    const float c = expf(logc[0]);

    const float tn    = sqrtf(ss);
    const float scale = fminf(MAX_NORM / fmaxf(tn, EPSV), 1.0f);

    float4 oa, ob;
    oa.x = a.x * scale; oa.y = a.y * scale; oa.z = a.z * scale; oa.w = a.w * scale;
    ob.x = b.x * scale; ob.y = b.y * scale; ob.z = b.z * scale; ob.w = b.w * scale;

    float4* o4 = (float4*)(ch + (size_t)row * D);
    o4[2 * lane]     = oa;
    o4[2 * lane + 1] = ob;

    union { ushort u[8]; uint4 v; } pk;
    pk.u[0] = f32_to_bf16(oa.x); pk.u[1] = f32_to_bf16(oa.y);
    pk.u[2] = f32_to_bf16(oa.z); pk.u[3] = f32_to_bf16(oa.w);
    pk.u[4] = f32_to_bf16(ob.x); pk.u[5] = f32_to_bf16(ob.y);
    pk.u[6] = f32_to_bf16(ob.z); pk.u[7] = f32_to_bf16(ob.w);
    ((uint4*)(cbf + (size_t)row * D))[lane] = pk.v;

    if (lane == 0) {
        const float sq = scale * scale * ss;
        y2raw[row] = sq;
        dyv[row]   = 1.0f - c * fminf(sq, MAX_NORM * MAX_NORM);
    }
}

// ---------------------------------------------------------------------------
// Kernel 3: bf16 MFMA GEMM + Poincare epilogue.
// 256x256 tile, BK=64, 8 waves (2Mx4N, each 128x64 = 8x4 frags).
// Fragment-order double-buffered LDS (128 KB), DEPTH-2 prefetch with
// COUNTED vmcnt (T4) + raw barriers (HK discipline) + inline-asm ds_read
// (defeats compiler alias-vmcnt(0)) + setprio around MFMA cluster (T5).
// Per K-tile: compute(p) -> s_barrier -> stage(p,t+2) -> vmcnt(8) -> s_barrier.
// Epilogue: per-wave LDS transpose (aliases staging LDS) + float4 stores.
// ---------------------------------------------------------------------------
#define BM 256
#define BN 256
#define BKT 64
#define EPST 68   // epilogue LDS row stride in floats

__global__ __launch_bounds__(512, 2)
void gemm_epi_kernel(const ushort* __restrict__ Abf,   // M x K bf16
                     const ushort* __restrict__ Bbf,   // N x K bf16
                     const float* __restrict__ x2raw,
                     const float* __restrict__ dxv,
                     const float* __restrict__ y2raw,
                     const float* __restrict__ dyv,
                     const float* __restrict__ logc,
                     float* __restrict__ out,          // M x N
                     int M, int N, int K) {
    // 128 KB: two buffers x (A 32 subtiles + B 32 subtiles) x 1KB.
    // Subtile s: rowgroup rg = s>>1 (16 rows), khalf = s&1 (32 k), stored in
    // exact MFMA fragment order (lane l -> row l&15, k (l>>4)*8).
    __shared__ __align__(16) ushort As[2][32 * 512];
    __shared__ __align__(16) ushort Bs[2][32 * 512];

    const int tid  = threadIdx.x;
    const int lane = tid & 63;
    const int wid  = tid >> 6;     // 0..7
    const int wm   = wid >> 2;     // 0..1  (128-row half)
    const int wn   = wid & 3;      // 0..3  (64-col quarter)

    const int bm = blockIdx.y;
    const int bn = blockIdx.x;

    const ushort* Ab = Abf + (size_t)bm * BM * K;
    const ushort* Bb = Bbf + (size_t)bn * BN * K;

    f32x4 acc[8][4];
#pragma unroll
    for (int m = 0; m < 8; m++)
#pragma unroll
        for (int n = 0; n < 4; n++) acc[m][n] = (f32x4){0.f, 0.f, 0.f, 0.f};

    // Per-lane fragment-order source offset within a 16x32 subtile.
    const size_t fragoff = (size_t)(lane & 15) * K + ((lane >> 4) * 8);

    // Stage one K-tile (64 KB) into buffer p: wave w covers subtiles 4w..4w+3
    // of both A and B (8 glds16 calls/wave -> vmcnt +8).
    auto stage = [&](int p, int k0) {
#pragma unroll
        for (int j = 0; j < 4; j++) {
            const int s  = wid * 4 + j;
            const int rg = s >> 1;
            const int kk = s & 1;
            const size_t goff = (size_t)(rg * 16) * K + k0 + kk * 32 + fragoff;
            glds16(Ab + goff, &As[p][s * 512]);
            glds16(Bb + goff, &Bs[p][s * 512]);
        }
    };

    // Prologue: depth-2 prefetch.
    stage(0, 0);
    stage(1, BKT);
    asm volatile("s_waitcnt vmcnt(8)" ::: "memory");   // tile 0 landed
    __builtin_amdgcn_s_barrier();

    const int NT = K / BKT;          // 8
    int p = 0;
    for (int t = 0; t < NT; t++) {
        // ---- compute on buffer p (inline-asm reads; no compiler vmcnt) ----
#pragma unroll
        for (int kk = 0; kk < 2; kk++) {
            short8 af[8], bfr[4];
#pragma unroll
            for (int m = 0; m < 8; m++)
                af[m] = ds_read128(&As[p][((wm * 8 + m) * 2 + kk) * 512 + lane * 8]);
#pragma unroll
            for (int n = 0; n < 4; n++)
                bfr[n] = ds_read128(&Bs[p][((wn * 4 + n) * 2 + kk) * 512 + lane * 8]);
            asm volatile("s_waitcnt lgkmcnt(0)" ::: "memory");
            __builtin_amdgcn_sched_barrier(0);          // rule #18: pin MFMAs after wait
            __builtin_amdgcn_s_setprio(1);
#pragma unroll
            for (int m = 0; m < 8; m++)
#pragma unroll
                for (int n = 0; n < 4; n++)
                    acc[m][n] = __builtin_amdgcn_mfma_f32_16x16x32_bf16(
                        af[m], bfr[n], acc[m][n], 0, 0, 0);
            __builtin_amdgcn_s_setprio(0);
        }

        __builtin_amdgcn_s_barrier();   // all waves done reading p

        if (t + 2 < NT) {
            stage(p, (t + 2) * BKT);    // outstanding: 8 (t+1) + 8 (t+2)
            asm volatile("s_waitcnt vmcnt(8)" ::: "memory");   // t+1 landed
            __builtin_amdgcn_s_barrier();                      // publish p^1
        } else if (t + 1 < NT) {
            asm volatile("s_waitcnt vmcnt(0)" ::: "memory");   // final tile landed
            __builtin_amdgcn_s_barrier();
        }
        p ^= 1;
    }

    __syncthreads();   // staging LDS -> epilogue reuse safety

    // ---------------- Epilogue: LDS transpose + coalesced stores ------------
    const float c   = expf(logc[0]);
    const float rsc = 1.0f / sqrtf(c);
    const int l16 = lane & 15;
    const int lg  = lane >> 4;

    float* ep = (float*)((char*)As + (size_t)wid * 4352);  // private [16][EPST]
    const int gr_base = bm * BM + wm * 128;
    const int gc_base = bn * BN + wn * 64;

#pragma unroll
    for (int m = 0; m < 8; m++) {
        // scatter this m-frag (16 rows x 64 cols) into the private region
#pragma unroll
        for (int n = 0; n < 4; n++)
#pragma unroll
            for (int r = 0; r < 4; r++)
                ep[(lg * 4 + r) * EPST + n * 16 + l16] = acc[m][n][r];
        asm volatile("s_waitcnt lgkmcnt(0)" ::: "memory");

        // read back row-major: 4 iters x (4 rows x 16 float4 chunks)
#pragma unroll
        for (int it = 0; it < 4; it++) {
            const int row = it * 4 + lg;                  // 0..15
            const int gr  = gr_base + m * 16 + row;
            const int gc  = gc_base + l16 * 4;
            float4 xy4 = *(const float4*)&ep[row * EPST + l16 * 4];
            const float rx  = x2raw[gr];
            const float dxr = dxv[gr];
            const float4 ry4 = *(const float4*)&y2raw[gc];
            const float4 dy4 = *(const float4*)&dyv[gc];
            float4 o;
            {
                const float rden = __builtin_amdgcn_rcpf(fmaxf(dxr * dy4.x, EPSV));
                float t = fmaxf(2.0f * c * (rx + ry4.x - 2.0f * xy4.x) * rden, EPSV);
                o.x = __logf(1.0f + t + __builtin_amdgcn_sqrtf(t * (t + 2.0f))) * rsc;
            }
            {
                const float rden = __builtin_amdgcn_rcpf(fmaxf(dxr * dy4.y, EPSV));
                float t = fmaxf(2.0f * c * (rx + ry4.y - 2.0f * xy4.y) * rden, EPSV);
                o.y = __logf(1.0f + t + __builtin_amdgcn_sqrtf(t * (t + 2.0f))) * rsc;
            }
            {
                const float rden = __builtin_amdgcn_rcpf(fmaxf(dxr * dy4.z, EPSV));
                float t = fmaxf(2.0f * c * (rx + ry4.z - 2.0f * xy4.z) * rden, EPSV);
                o.z = __logf(1.0f + t + __builtin_amdgcn_sqrtf(t * (t + 2.0f))) * rsc;
            }
            {
                const float rden = __builtin_amdgcn_rcpf(fmaxf(dxr * dy4.w, EPSV));
                float t = fmaxf(2.0f * c * (rx + ry4.w - 2.0f * xy4.w) * rden, EPSV);
                o.w = __logf(1.0f + t + __builtin_amdgcn_sqrtf(t * (t + 2.0f))) * rsc;
            }
            *(float4*)&out[(size_t)gr * N + gc] = o;
        }
        asm volatile("s_waitcnt lgkmcnt(0)" ::: "memory");
    }
}

// ---------------------------------------------------------------------------
extern "C" void kernel_launch(void* const* d_in, const int* in_sizes, int n_in,
                              void* d_out, int out_size, void* d_ws, size_t ws_size,
                              hipStream_t stream) {
    const float* emb  = (const float*)d_in[0];   // (B, D) f32
    const float* logc = (const float*)d_in[1];   // scalar f32
    const float* cen  = (const float*)d_in[2];   // (C, D) f32

    const int D = 512;
    const int B = in_sizes[0] / D;   // 8192
    const int C = in_sizes[2] / D;   // 4096

    float* out   = (float*)d_out;
    float* dists = out;                          // B*C
    float* xh    = out + (size_t)B * C;          // B*D
    float* ch    = xh + (size_t)B * D;           // C*D

    char* ws = (char*)d_ws;
    size_t off = 0;
    auto alloc = [&](size_t bytes) -> char* {
        char* p = ws + off;
        off += (bytes + 255) & ~(size_t)255;
        return p;
    };
    ushort* xbf   = (ushort*)alloc((size_t)B * D * sizeof(ushort));
    ushort* cbf   = (ushort*)alloc((size_t)C * D * sizeof(ushort));
    float*  x2raw = (float*)alloc((size_t)B * sizeof(float));
    float*  dxv   = (float*)alloc((size_t)B * sizeof(float));
    float*  y2raw = (float*)alloc((size_t)C * sizeof(float));
    float*  dyv   = (float*)alloc((size_t)C * sizeof(float));

    rows_emb_kernel<<<B, 64, 0, stream>>>(emb, logc, xh, xbf, x2raw, dxv);
    rows_cen_kernel<<<C, 64, 0, stream>>>(cen, logc, ch, cbf, y2raw, dyv);

    dim3 grid(C / BN, B / BM);   // (16, 32)
    gemm_epi_kernel<<<grid, 512, 0, stream>>>(xbf, cbf, x2raw, dxv, y2raw, dyv,
                                              logc, dists, B, C, D);
}

// Round 11
// 88.852 us; speedup vs baseline: 1.9566x; 1.0531x over previous
//
#include <hip/hip_runtime.h>
#include <math.h>

#define EPSV 1e-6f
#define MAX_NORM (1.0f - 1e-3f)

typedef __attribute__((ext_vector_type(8))) short short8;   // 8 bf16 = 4 VGPRs
typedef __attribute__((ext_vector_type(4))) float f32x4;    // MFMA acc

// f32 -> bf16 (round-to-nearest-even), returns raw 16-bit pattern
__device__ inline ushort f32_to_bf16(float f) {
    union { float f; uint32_t u; } cv;
    cv.f = f;
    uint32_t u = cv.u;
    u += 0x7FFFu + ((u >> 16) & 1u);
    return (ushort)(u >> 16);
}

// async global -> LDS, 16 bytes per lane (dest = uniform base + lane*16)
__device__ inline void glds16(const ushort* gsrc, ushort* ldsdst) {
    auto* g = (const __attribute__((address_space(1))) uint32_t*)gsrc;
    auto* l = (__attribute__((address_space(3))) uint32_t*)ldsdst;
    __builtin_amdgcn_global_load_lds(g, l, 16, 0, 0);
}

// inline-asm ds_read_b128: opaque to compiler alias analysis (no auto vmcnt)
__device__ inline short8 ds_read128(const ushort* p) {
    auto* l3 = (const __attribute__((address_space(3))) ushort*)p;
    const uint32_t addr = (uint32_t)(uintptr_t)l3;
    short8 v;
    asm volatile("ds_read_b128 %0, %1" : "=&v"(v) : "v"(addr));
    return v;
}

// ---------------------------------------------------------------------------
// Kernel 1: expmap0 + clip for embeddings. One wave (64 lanes) per row, D=512.
// ---------------------------------------------------------------------------
__global__ void rows_emb_kernel(const float* __restrict__ emb,
                                const float* __restrict__ logc,
                                float* __restrict__ xh,
                                ushort* __restrict__ xbf,
                                float* __restrict__ x2raw,
                                float* __restrict__ dxv) {
    const int D = 512;
    const int row = blockIdx.x;
    const int lane = threadIdx.x;   // 0..63

    const float4* r4 = (const float4*)(emb + (size_t)row * D);
    float4 a = r4[2 * lane];
    float4 b = r4[2 * lane + 1];

    float ss = a.x * a.x + a.y * a.y + a.z * a.z + a.w * a.w
             + b.x * b.x + b.y * b.y + b.z * b.z + b.w * b.w;
#pragma unroll
    for (int off = 32; off > 0; off >>= 1) ss += __shfl_xor(ss, off, 64);

    const float c  = expf(logc[0]);
    const float sc = sqrtf(c);

    const float tn    = sqrtf(ss);
    const float vn    = fmaxf(tn, EPSV);
    const float coeff = tanhf(sc * vn) / (sc * vn);
    const float pre   = coeff * tn;
    const float fac   = fminf(MAX_NORM / fmaxf(pre, EPSV), 1.0f);
    const float scale = coeff * fac;

    float4 oa, ob;
    oa.x = a.x * scale; oa.y = a.y * scale; oa.z = a.z * scale; oa.w = a.w * scale;
    ob.x = b.x * scale; ob.y = b.y * scale; ob.z = b.z * scale; ob.w = b.w * scale;

    float4* o4 = (float4*)(xh + (size_t)row * D);
    o4[2 * lane]     = oa;
    o4[2 * lane + 1] = ob;

    union { ushort u[8]; uint4 v; } pk;
    pk.u[0] = f32_to_bf16(oa.x); pk.u[1] = f32_to_bf16(oa.y);
    pk.u[2] = f32_to_bf16(oa.z); pk.u[3] = f32_to_bf16(oa.w);
    pk.u[4] = f32_to_bf16(ob.x); pk.u[5] = f32_to_bf16(ob.y);
    pk.u[6] = f32_to_bf16(ob.z); pk.u[7] = f32_to_bf16(ob.w);
    ((uint4*)(xbf + (size_t)row * D))[lane] = pk.v;

    if (lane == 0) {
        const float sq = scale * scale * ss;
        x2raw[row] = sq;
        dxv[row]   = 1.0f - c * fminf(sq, MAX_NORM * MAX_NORM);
    }
}

// ---------------------------------------------------------------------------
// Kernel 2: clip-only for centroids. One wave per row, D=512.
// ---------------------------------------------------------------------------
__global__ void rows_cen_kernel(const float* __restrict__ cen,
                                const float* __restrict__ logc,
                                float* __restrict__ ch,
                                ushort* __restrict__ cbf,
                                float* __restrict__ y2raw,
                                float* __restrict__ dyv) {
    const int D = 512;
    const int row = blockIdx.x;
    const int lane = threadIdx.x;

    const float4* r4 = (const float4*)(cen + (size_t)row * D);
    float4 a = r4[2 * lane];
    float4 b = r4[2 * lane + 1];

    float ss = a.x * a.x + a.y * a.y + a.z * a.z + a.w * a.w
             + b.x * b.x + b.y * b.y + b.z * b.z + b.w * b.w;
#pragma unroll
    for (int off = 32; off > 0; off >>= 1) ss += __shfl_xor(ss, off, 64);

    const float c = expf(logc[0]);

    const float tn    = sqrtf(ss);
    const float scale = fminf(MAX_NORM / fmaxf(tn, EPSV), 1.0f);

    float4 oa, ob;
    oa.x = a.x * scale; oa.y = a.y * scale; oa.z = a.z * scale; oa.w = a.w * scale;
    ob.x = b.x * scale; ob.y = b.y * scale; ob.z = b.z * scale; ob.w = b.w * scale;

    float4* o4 = (float4*)(ch + (size_t)row * D);
    o4[2 * lane]     = oa;
    o4[2 * lane + 1] = ob;

    union { ushort u[8]; uint4 v; } pk;
    pk.u[0] = f32_to_bf16(oa.x); pk.u[1] = f32_to_bf16(oa.y);
    pk.u[2] = f32_to_bf16(oa.z); pk.u[3] = f32_to_bf16(oa.w);
    pk.u[4] = f32_to_bf16(ob.x); pk.u[5] = f32_to_bf16(ob.y);
    pk.u[6] = f32_to_bf16(ob.z); pk.u[7] = f32_to_bf16(ob.w);
    ((uint4*)(cbf + (size_t)row * D))[lane] = pk.v;

    if (lane == 0) {
        const float sq = scale * scale * ss;
        y2raw[row] = sq;
        dyv[row]   = 1.0f - c * fminf(sq, MAX_NORM * MAX_NORM);
    }
}

// ---------------------------------------------------------------------------
// Kernel 3: bf16 MFMA GEMM + Poincare epilogue.
// 256x256 tile, BKT=32, 8 waves (2Mx4N, each 128x64 = 8x4 frags).
// Fragment-order double-buffered LDS -- now 64 KB total => 2 BLOCKS/CU
// (4 waves/SIMD): cross-block wave overlap hides ds_read latency, barrier
// arrival, and epilogue bursts (the m97/m114 mechanism R9/R10 lacked at
// 128 KB / 1 block/CU). Depth-2 prefetch, counted vmcnt(4) at tile
// boundaries, inline-asm ds_read (no compiler vmcnt0), setprio on MFMA.
// Epilogue: per-wave LDS transpose (aliases staging LDS) + float4 stores.
// ---------------------------------------------------------------------------
#define BM 256
#define BN 256
#define BKT 32
#define EPST 68   // epilogue LDS row stride in floats

__global__ __launch_bounds__(512, 2)
void gemm_epi_kernel(const ushort* __restrict__ Abf,   // M x K bf16
                     const ushort* __restrict__ Bbf,   // N x K bf16
                     const float* __restrict__ x2raw,
                     const float* __restrict__ dxv,
                     const float* __restrict__ y2raw,
                     const float* __restrict__ dyv,
                     const float* __restrict__ logc,
                     float* __restrict__ out,          // M x N
                     int M, int N, int K) {
    // 64 KB: [A p0 16K][A p1 16K][B p0 16K][B p1 16K].
    // Per buffer: 16 subtiles x 1KB; subtile s = rows 16s..16s+15 x 32 k in
    // exact MFMA fragment order (lane l -> row l&15, k (l>>4)*8).
    __shared__ __align__(16) char smem[65536];

    const int tid  = threadIdx.x;
    const int lane = tid & 63;
    const int wid  = tid >> 6;     // 0..7
    const int wm   = wid >> 2;     // 0..1  (128-row half)
    const int wn   = wid & 3;      // 0..3  (64-col quarter)

    const int bm = blockIdx.y;
    const int bn = blockIdx.x;

    const ushort* Ab = Abf + (size_t)bm * BM * K;
    const ushort* Bb = Bbf + (size_t)bn * BN * K;

    f32x4 acc[8][4];
#pragma unroll
    for (int m = 0; m < 8; m++)
#pragma unroll
        for (int n = 0; n < 4; n++) acc[m][n] = (f32x4){0.f, 0.f, 0.f, 0.f};

    // Per-lane fragment-order source offset within a 16x32 subtile.
    const size_t fragoff = (size_t)(lane & 15) * K + ((lane >> 4) * 8);

    auto Asb = [&](int p) { return (ushort*)(smem + p * 16384); };
    auto Bsb = [&](int p) { return (ushort*)(smem + 32768 + p * 16384); };

    // Stage one K-tile (32 KB) into buffer p: wave w covers subtiles 2w,2w+1
    // of both A and B (4 glds16 calls/wave -> vmcnt +4).
    auto stage = [&](int p, int k0) {
#pragma unroll
        for (int j = 0; j < 2; j++) {
            const int s = wid * 2 + j;
            const size_t goff = (size_t)(s * 16) * K + k0 + fragoff;
            glds16(Ab + goff, Asb(p) + s * 512);
            glds16(Bb + goff, Bsb(p) + s * 512);
        }
    };

    // Prologue: depth-2 prefetch.
    stage(0, 0);
    stage(1, BKT);
    asm volatile("s_waitcnt vmcnt(4)" ::: "memory");   // tile 0 landed
    __builtin_amdgcn_s_barrier();

    const int NT = K / BKT;          // 16
    int p = 0;
    for (int t = 0; t < NT; t++) {
        // ---- compute on buffer p (inline-asm reads; no compiler vmcnt) ----
        short8 af[8], bfr[4];
#pragma unroll
        for (int m = 0; m < 8; m++)
            af[m] = ds_read128(Asb(p) + (wm * 8 + m) * 512 + lane * 8);
#pragma unroll
        for (int n = 0; n < 4; n++)
            bfr[n] = ds_read128(Bsb(p) + (wn * 4 + n) * 512 + lane * 8);
        asm volatile("s_waitcnt lgkmcnt(0)" ::: "memory");
        __builtin_amdgcn_sched_barrier(0);          // rule #18: pin MFMAs after wait
        __builtin_amdgcn_s_setprio(1);
#pragma unroll
        for (int m = 0; m < 8; m++)
#pragma unroll
            for (int n = 0; n < 4; n++)
                acc[m][n] = __builtin_amdgcn_mfma_f32_16x16x32_bf16(
                    af[m], bfr[n], acc[m][n], 0, 0, 0);
        __builtin_amdgcn_s_setprio(0);

        __builtin_amdgcn_s_barrier();   // all waves done reading p

        if (t + 2 < NT) {
            stage(p, (t + 2) * BKT);    // outstanding: 4 (t+1) + 4 (t+2)
            asm volatile("s_waitcnt vmcnt(4)" ::: "memory");   // t+1 landed
            __builtin_amdgcn_s_barrier();                      // publish p^1
        } else if (t + 1 < NT) {
            asm volatile("s_waitcnt vmcnt(0)" ::: "memory");   // final tile landed
            __builtin_amdgcn_s_barrier();
        }
        p ^= 1;
    }

    __syncthreads();   // staging LDS -> epilogue reuse safety

    // ---------------- Epilogue: LDS transpose + coalesced stores ------------
    const float c   = expf(logc[0]);
    const float rsc = 1.0f / sqrtf(c);
    const int l16 = lane & 15;
    const int lg  = lane >> 4;

    float* ep = (float*)(smem + (size_t)wid * 4352);  // private [16][EPST]
    const int gr_base = bm * BM + wm * 128;
    const int gc_base = bn * BN + wn * 64;

#pragma unroll
    for (int m = 0; m < 8; m++) {
        // scatter this m-frag (16 rows x 64 cols) into the private region
#pragma unroll
        for (int n = 0; n < 4; n++)
#pragma unroll
            for (int r = 0; r < 4; r++)
                ep[(lg * 4 + r) * EPST + n * 16 + l16] = acc[m][n][r];
        asm volatile("s_waitcnt lgkmcnt(0)" ::: "memory");

        // read back row-major: 4 iters x (4 rows x 16 float4 chunks)
#pragma unroll
        for (int it = 0; it < 4; it++) {
            const int row = it * 4 + lg;                  // 0..15
            const int gr  = gr_base + m * 16 + row;
            const int gc  = gc_base + l16 * 4;
            float4 xy4 = *(const float4*)&ep[row * EPST + l16 * 4];
            const float rx  = x2raw[gr];
            const float dxr = dxv[gr];
            const float4 ry4 = *(const float4*)&y2raw[gc];
            const float4 dy4 = *(const float4*)&dyv[gc];
            float4 o;
            {
                const float rden = __builtin_amdgcn_rcpf(fmaxf(dxr * dy4.x, EPSV));
                float t = fmaxf(2.0f * c * (rx + ry4.x - 2.0f * xy4.x) * rden, EPSV);
                o.x = __logf(1.0f + t + __builtin_amdgcn_sqrtf(t * (t + 2.0f))) * rsc;
            }
            {
                const float rden = __builtin_amdgcn_rcpf(fmaxf(dxr * dy4.y, EPSV));
                float t = fmaxf(2.0f * c * (rx + ry4.y - 2.0f * xy4.y) * rden, EPSV);
                o.y = __logf(1.0f + t + __builtin_amdgcn_sqrtf(t * (t + 2.0f))) * rsc;
            }
            {
                const float rden = __builtin_amdgcn_rcpf(fmaxf(dxr * dy4.z, EPSV));
                float t = fmaxf(2.0f * c * (rx + ry4.z - 2.0f * xy4.z) * rden, EPSV);
                o.z = __logf(1.0f + t + __builtin_amdgcn_sqrtf(t * (t + 2.0f))) * rsc;
            }
            {
                const float rden = __builtin_amdgcn_rcpf(fmaxf(dxr * dy4.w, EPSV));
                float t = fmaxf(2.0f * c * (rx + ry4.w - 2.0f * xy4.w) * rden, EPSV);
                o.w = __logf(1.0f + t + __builtin_amdgcn_sqrtf(t * (t + 2.0f))) * rsc;
            }
            *(float4*)&out[(size_t)gr * N + gc] = o;
        }
        asm volatile("s_waitcnt lgkmcnt(0)" ::: "memory");
    }
}

// ---------------------------------------------------------------------------
extern "C" void kernel_launch(void* const* d_in, const int* in_sizes, int n_in,
                              void* d_out, int out_size, void* d_ws, size_t ws_size,
                              hipStream_t stream) {
    const float* emb  = (const float*)d_in[0];   // (B, D) f32
    const float* logc = (const float*)d_in[1];   // scalar f32
    const float* cen  = (const float*)d_in[2];   // (C, D) f32

    const int D = 512;
    const int B = in_sizes[0] / D;   // 8192
    const int C = in_sizes[2] / D;   // 4096

    float* out   = (float*)d_out;
    float* dists = out;                          // B*C
    float* xh    = out + (size_t)B * C;          // B*D
    float* ch    = xh + (size_t)B * D;           // C*D

    char* ws = (char*)d_ws;
    size_t off = 0;
    auto alloc = [&](size_t bytes) -> char* {
        char* p = ws + off;
        off += (bytes + 255) & ~(size_t)255;
        return p;
    };
    ushort* xbf   = (ushort*)alloc((size_t)B * D * sizeof(ushort));
    ushort* cbf   = (ushort*)alloc((size_t)C * D * sizeof(ushort));
    float*  x2raw = (float*)alloc((size_t)B * sizeof(float));
    float*  dxv   = (float*)alloc((size_t)B * sizeof(float));
    float*  y2raw = (float*)alloc((size_t)C * sizeof(float));
    float*  dyv   = (float*)alloc((size_t)C * sizeof(float));

    rows_emb_kernel<<<B, 64, 0, stream>>>(emb, logc, xh, xbf, x2raw, dxv);
    rows_cen_kernel<<<C, 64, 0, stream>>>(cen, logc, ch, cbf, y2raw, dyv);

    dim3 grid(C / BN, B / BM);   // (16, 32)
    gemm_epi_kernel<<<grid, 512, 0, stream>>>(xbf, cbf, x2raw, dxv, y2raw, dyv,
                                              logc, dists, B, C, D);
}

// Round 12
// 88.792 us; speedup vs baseline: 1.9580x; 1.0007x over previous
//
#include <hip/hip_runtime.h>
#include <math.h>

#define EPSV 1e-6f
#define MAX_NORM (1.0f - 1e-3f)

typedef __attribute__((ext_vector_type(8))) short short8;   // 8 bf16 = 4 VGPRs
typedef __attribute__((ext_vector_type(4))) float f32x4;    // MFMA acc

// f32 -> bf16 (round-to-nearest-even), returns raw 16-bit pattern
__device__ inline ushort f32_to_bf16(float f) {
    union { float f; uint32_t u; } cv;
    cv.f = f;
    uint32_t u = cv.u;
    u += 0x7FFFu + ((u >> 16) & 1u);
    return (ushort)(u >> 16);
}

// async global -> LDS, 16 bytes per lane (dest = uniform base + lane*16)
__device__ inline void glds16(const ushort* gsrc, ushort* ldsdst) {
    auto* g = (const __attribute__((address_space(1))) uint32_t*)gsrc;
    auto* l = (__attribute__((address_space(3))) uint32_t*)ldsdst;
    __builtin_amdgcn_global_load_lds(g, l, 16, 0, 0);
}

// inline-asm ds_read_b128: opaque to compiler alias analysis (no auto vmcnt)
__device__ inline short8 ds_read128(const ushort* p) {
    auto* l3 = (const __attribute__((address_space(3))) ushort*)p;
    const uint32_t addr = (uint32_t)(uintptr_t)l3;
    short8 v;
    asm volatile("ds_read_b128 %0, %1" : "=&v"(v) : "v"(addr));
    return v;
}

// ---------------------------------------------------------------------------
// Kernel 1: expmap0 + clip for embeddings. One wave (64 lanes) per row, D=512.
// ---------------------------------------------------------------------------
__global__ void rows_emb_kernel(const float* __restrict__ emb,
                                const float* __restrict__ logc,
                                float* __restrict__ xh,
                                ushort* __restrict__ xbf,
                                float* __restrict__ x2raw,
                                float* __restrict__ dxv) {
    const int D = 512;
    const int row = blockIdx.x;
    const int lane = threadIdx.x;   // 0..63

    const float4* r4 = (const float4*)(emb + (size_t)row * D);
    float4 a = r4[2 * lane];
    float4 b = r4[2 * lane + 1];

    float ss = a.x * a.x + a.y * a.y + a.z * a.z + a.w * a.w
             + b.x * b.x + b.y * b.y + b.z * b.z + b.w * b.w;
#pragma unroll
    for (int off = 32; off > 0; off >>= 1) ss += __shfl_xor(ss, off, 64);

    const float c  = expf(logc[0]);
    const float sc = sqrtf(c);

    const float tn    = sqrtf(ss);
    const float vn    = fmaxf(tn, EPSV);
    const float coeff = tanhf(sc * vn) / (sc * vn);
    const float pre   = coeff * tn;
    const float fac   = fminf(MAX_NORM / fmaxf(pre, EPSV), 1.0f);
    const float scale = coeff * fac;

    float4 oa, ob;
    oa.x = a.x * scale; oa.y = a.y * scale; oa.z = a.z * scale; oa.w = a.w * scale;
    ob.x = b.x * scale; ob.y = b.y * scale; ob.z = b.z * scale; ob.w = b.w * scale;

    float4* o4 = (float4*)(xh + (size_t)row * D);
    o4[2 * lane]     = oa;
    o4[2 * lane + 1] = ob;

    union { ushort u[8]; uint4 v; } pk;
    pk.u[0] = f32_to_bf16(oa.x); pk.u[1] = f32_to_bf16(oa.y);
    pk.u[2] = f32_to_bf16(oa.z); pk.u[3] = f32_to_bf16(oa.w);
    pk.u[4] = f32_to_bf16(ob.x); pk.u[5] = f32_to_bf16(ob.y);
    pk.u[6] = f32_to_bf16(ob.z); pk.u[7] = f32_to_bf16(ob.w);
    ((uint4*)(xbf + (size_t)row * D))[lane] = pk.v;

    if (lane == 0) {
        const float sq = scale * scale * ss;
        x2raw[row] = sq;
        dxv[row]   = 1.0f - c * fminf(sq, MAX_NORM * MAX_NORM);
    }
}

// ---------------------------------------------------------------------------
// Kernel 2: clip-only for centroids. One wave per row, D=512.
// ---------------------------------------------------------------------------
__global__ void rows_cen_kernel(const float* __restrict__ cen,
                                const float* __restrict__ logc,
                                float* __restrict__ ch,
                                ushort* __restrict__ cbf,
                                float* __restrict__ y2raw,
                                float* __restrict__ dyv) {
    const int D = 512;
    const int row = blockIdx.x;
    const int lane = threadIdx.x;

    const float4* r4 = (const float4*)(cen + (size_t)row * D);
    float4 a = r4[2 * lane];
    float4 b = r4[2 * lane + 1];

    float ss = a.x * a.x + a.y * a.y + a.z * a.z + a.w * a.w
             + b.x * b.x + b.y * b.y + b.z * b.z + b.w * b.w;
#pragma unroll
    for (int off = 32; off > 0; off >>= 1) ss += __shfl_xor(ss, off, 64);

    const float c = expf(logc[0]);

    const float tn    = sqrtf(ss);
    const float scale = fminf(MAX_NORM / fmaxf(tn, EPSV), 1.0f);

    float4 oa, ob;
    oa.x = a.x * scale; oa.y = a.y * scale; oa.z = a.z * scale; oa.w = a.w * scale;
    ob.x = b.x * scale; ob.y = b.y * scale; ob.z = b.z * scale; ob.w = b.w * scale;

    float4* o4 = (float4*)(ch + (size_t)row * D);
    o4[2 * lane]     = oa;
    o4[2 * lane + 1] = ob;

    union { ushort u[8]; uint4 v; } pk;
    pk.u[0] = f32_to_bf16(oa.x); pk.u[1] = f32_to_bf16(oa.y);
    pk.u[2] = f32_to_bf16(oa.z); pk.u[3] = f32_to_bf16(oa.w);
    pk.u[4] = f32_to_bf16(ob.x); pk.u[5] = f32_to_bf16(ob.y);
    pk.u[6] = f32_to_bf16(ob.z); pk.u[7] = f32_to_bf16(ob.w);
    ((uint4*)(cbf + (size_t)row * D))[lane] = pk.v;

    if (lane == 0) {
        const float sq = scale * scale * ss;
        y2raw[row] = sq;
        dyv[row]   = 1.0f - c * fminf(sq, MAX_NORM * MAX_NORM);
    }
}

// ---------------------------------------------------------------------------
// Kernel 3: bf16 MFMA GEMM + Poincare epilogue.
// 256x256 tile, BKT=32, 8 waves (2Mx4N, each 128x64 = 8x4 frags), 2 blk/CU.
// QUADRANT-PIPELINED compute: per K-tile, 4 quadrants of 8 MFMA; reads for
// quadrant q+1 issued before waiting (counted lgkmcnt(2)) so ds_read latency
// hides under quadrant q's MFMA (the m196 per-phase interleave lever).
// Depth-2 prefetch with counted vmcnt(4); fragment-order zero-conflict LDS;
// per-wave LDS-transpose epilogue with float4 stores.
// ---------------------------------------------------------------------------
#define BM 256
#define BN 256
#define BKT 32
#define EPST 68   // epilogue LDS row stride in floats

__global__ __launch_bounds__(512, 2)
void gemm_epi_kernel(const ushort* __restrict__ Abf,   // M x K bf16
                     const ushort* __restrict__ Bbf,   // N x K bf16
                     const float* __restrict__ x2raw,
                     const float* __restrict__ dxv,
                     const float* __restrict__ y2raw,
                     const float* __restrict__ dyv,
                     const float* __restrict__ logc,
                     float* __restrict__ out,          // M x N
                     int M, int N, int K) {
    // 64 KB: [A p0 16K][A p1 16K][B p0 16K][B p1 16K].
    // Per buffer: 16 subtiles x 1KB; subtile s = rows 16s..16s+15 x 32 k in
    // exact MFMA fragment order (lane l -> row l&15, k (l>>4)*8).
    __shared__ __align__(16) char smem[65536];

    const int tid  = threadIdx.x;
    const int lane = tid & 63;
    const int wid  = tid >> 6;     // 0..7
    const int wm   = wid >> 2;     // 0..1  (128-row half)
    const int wn   = wid & 3;      // 0..3  (64-col quarter)

    const int bm = blockIdx.y;
    const int bn = blockIdx.x;

    const ushort* Ab = Abf + (size_t)bm * BM * K;
    const ushort* Bb = Bbf + (size_t)bn * BN * K;

    f32x4 acc[8][4];
#pragma unroll
    for (int m = 0; m < 8; m++)
#pragma unroll
        for (int n = 0; n < 4; n++) acc[m][n] = (f32x4){0.f, 0.f, 0.f, 0.f};

    // Per-lane fragment-order source offset within a 16x32 subtile.
    const size_t fragoff = (size_t)(lane & 15) * K + ((lane >> 4) * 8);

    auto Asb = [&](int p) { return (ushort*)(smem + p * 16384); };
    auto Bsb = [&](int p) { return (ushort*)(smem + 32768 + p * 16384); };

    // Stage one K-tile (32 KB) into buffer p: wave w covers subtiles 2w,2w+1
    // of both A and B (4 glds16 calls/wave -> vmcnt +4).
    auto stage = [&](int p, int k0) {
#pragma unroll
        for (int j = 0; j < 2; j++) {
            const int s = wid * 2 + j;
            const size_t goff = (size_t)(s * 16) * K + k0 + fragoff;
            glds16(Ab + goff, Asb(p) + s * 512);
            glds16(Bb + goff, Bsb(p) + s * 512);
        }
    };

    // Prologue: depth-2 prefetch.
    stage(0, 0);
    stage(1, BKT);
    asm volatile("s_waitcnt vmcnt(4)" ::: "memory");   // tile 0 landed
    __builtin_amdgcn_s_barrier();

    const int NT = K / BKT;          // 16
    int p = 0;
    for (int t = 0; t < NT; t++) {
        // ---- quadrant-pipelined compute on buffer p ----
        short8 af[8], bfr[4];
#pragma unroll
        for (int n = 0; n < 4; n++)
            bfr[n] = ds_read128(Bsb(p) + (wn * 4 + n) * 512 + lane * 8);
        af[0] = ds_read128(Asb(p) + (wm * 8 + 0) * 512 + lane * 8);
        af[1] = ds_read128(Asb(p) + (wm * 8 + 1) * 512 + lane * 8);

#pragma unroll
        for (int q = 0; q < 4; q++) {
            if (q < 3) {   // issue next quadrant's A-pair before waiting
                af[2 * q + 2] = ds_read128(Asb(p) + (wm * 8 + 2 * q + 2) * 512 + lane * 8);
                af[2 * q + 3] = ds_read128(Asb(p) + (wm * 8 + 2 * q + 3) * 512 + lane * 8);
                asm volatile("s_waitcnt lgkmcnt(2)" ::: "memory");  // cur reads done
            } else {
                asm volatile("s_waitcnt lgkmcnt(0)" ::: "memory");
            }
            __builtin_amdgcn_sched_barrier(0);     // rule #18: MFMAs after wait
            __builtin_amdgcn_s_setprio(1);
#pragma unroll
            for (int mm = 0; mm < 2; mm++)
#pragma unroll
                for (int n = 0; n < 4; n++)
                    acc[2 * q + mm][n] = __builtin_amdgcn_mfma_f32_16x16x32_bf16(
                        af[2 * q + mm], bfr[n], acc[2 * q + mm][n], 0, 0, 0);
            __builtin_amdgcn_s_setprio(0);
        }

        __builtin_amdgcn_s_barrier();   // all waves done reading p

        if (t + 2 < NT) {
            stage(p, (t + 2) * BKT);    // outstanding: 4 (t+1) + 4 (t+2)
            asm volatile("s_waitcnt vmcnt(4)" ::: "memory");   // t+1 landed
            __builtin_amdgcn_s_barrier();                      // publish p^1
        } else if (t + 1 < NT) {
            asm volatile("s_waitcnt vmcnt(0)" ::: "memory");   // final tile landed
            __builtin_amdgcn_s_barrier();
        }
        p ^= 1;
    }

    __syncthreads();   // staging LDS -> epilogue reuse safety

    // ---------------- Epilogue: LDS transpose + coalesced stores ------------
    const float c   = expf(logc[0]);
    const float rsc = 1.0f / sqrtf(c);
    const int l16 = lane & 15;
    const int lg  = lane >> 4;

    float* ep = (float*)(smem + (size_t)wid * 4352);  // private [16][EPST]
    const int gr_base = bm * BM + wm * 128;
    const int gc_base = bn * BN + wn * 64;

#pragma unroll
    for (int m = 0; m < 8; m++) {
        // scatter this m-frag (16 rows x 64 cols) into the private region
#pragma unroll
        for (int n = 0; n < 4; n++)
#pragma unroll
            for (int r = 0; r < 4; r++)
                ep[(lg * 4 + r) * EPST + n * 16 + l16] = acc[m][n][r];
        asm volatile("s_waitcnt lgkmcnt(0)" ::: "memory");

        // read back row-major: 4 iters x (4 rows x 16 float4 chunks)
#pragma unroll
        for (int it = 0; it < 4; it++) {
            const int row = it * 4 + lg;                  // 0..15
            const int gr  = gr_base + m * 16 + row;
            const int gc  = gc_base + l16 * 4;
            float4 xy4 = *(const float4*)&ep[row * EPST + l16 * 4];
            const float rx  = x2raw[gr];
            const float dxr = dxv[gr];
            const float4 ry4 = *(const float4*)&y2raw[gc];
            const float4 dy4 = *(const float4*)&dyv[gc];
            float4 o;
            {
                const float rden = __builtin_amdgcn_rcpf(fmaxf(dxr * dy4.x, EPSV));
                float t = fmaxf(2.0f * c * (rx + ry4.x - 2.0f * xy4.x) * rden, EPSV);
                o.x = __logf(1.0f + t + __builtin_amdgcn_sqrtf(t * (t + 2.0f))) * rsc;
            }
            {
                const float rden = __builtin_amdgcn_rcpf(fmaxf(dxr * dy4.y, EPSV));
                float t = fmaxf(2.0f * c * (rx + ry4.y - 2.0f * xy4.y) * rden, EPSV);
                o.y = __logf(1.0f + t + __builtin_amdgcn_sqrtf(t * (t + 2.0f))) * rsc;
            }
            {
                const float rden = __builtin_amdgcn_rcpf(fmaxf(dxr * dy4.z, EPSV));
                float t = fmaxf(2.0f * c * (rx + ry4.z - 2.0f * xy4.z) * rden, EPSV);
                o.z = __logf(1.0f + t + __builtin_amdgcn_sqrtf(t * (t + 2.0f))) * rsc;
            }
            {
                const float rden = __builtin_amdgcn_rcpf(fmaxf(dxr * dy4.w, EPSV));
                float t = fmaxf(2.0f * c * (rx + ry4.w - 2.0f * xy4.w) * rden, EPSV);
                o.w = __logf(1.0f + t + __builtin_amdgcn_sqrtf(t * (t + 2.0f))) * rsc;
            }
            *(float4*)&out[(size_t)gr * N + gc] = o;
        }
        asm volatile("s_waitcnt lgkmcnt(0)" ::: "memory");
    }
}

// ---------------------------------------------------------------------------
extern "C" void kernel_launch(void* const* d_in, const int* in_sizes, int n_in,
                              void* d_out, int out_size, void* d_ws, size_t ws_size,
                              hipStream_t stream) {
    const float* emb  = (const float*)d_in[0];   // (B, D) f32
    const float* logc = (const float*)d_in[1];   // scalar f32
    const float* cen  = (const float*)d_in[2];   // (C, D) f32

    const int D = 512;
    const int B = in_sizes[0] / D;   // 8192
    const int C = in_sizes[2] / D;   // 4096

    float* out   = (float*)d_out;
    float* dists = out;                          // B*C
    float* xh    = out + (size_t)B * C;          // B*D
    float* ch    = xh + (size_t)B * D;           // C*D

    char* ws = (char*)d_ws;
    size_t off = 0;
    auto alloc = [&](size_t bytes) -> char* {
        char* p = ws + off;
        off += (bytes + 255) & ~(size_t)255;
        return p;
    };
    ushort* xbf   = (ushort*)alloc((size_t)B * D * sizeof(ushort));
    ushort* cbf   = (ushort*)alloc((size_t)C * D * sizeof(ushort));
    float*  x2raw = (float*)alloc((size_t)B * sizeof(float));
    float*  dxv   = (float*)alloc((size_t)B * sizeof(float));
    float*  y2raw = (float*)alloc((size_t)C * sizeof(float));
    float*  dyv   = (float*)alloc((size_t)C * sizeof(float));

    rows_emb_kernel<<<B, 64, 0, stream>>>(emb, logc, xh, xbf, x2raw, dxv);
    rows_cen_kernel<<<C, 64, 0, stream>>>(cen, logc, ch, cbf, y2raw, dyv);

    dim3 grid(C / BN, B / BM);   // (16, 32)
    gemm_epi_kernel<<<grid, 512, 0, stream>>>(xbf, cbf, x2raw, dxv, y2raw, dyv,
                                              logc, dists, B, C, D);
}

// Round 13
// 86.985 us; speedup vs baseline: 1.9986x; 1.0208x over previous
//
#include <hip/hip_runtime.h>
#include <math.h>

#define EPSV 1e-6f
#define MAX_NORM (1.0f - 1e-3f)

typedef __attribute__((ext_vector_type(8))) short short8;   // 8 bf16 = 4 VGPRs
typedef __attribute__((ext_vector_type(4))) float f32x4;    // MFMA acc

// f32 -> bf16 (round-to-nearest-even), returns raw 16-bit pattern
__device__ inline ushort f32_to_bf16(float f) {
    union { float f; uint32_t u; } cv;
    cv.f = f;
    uint32_t u = cv.u;
    u += 0x7FFFu + ((u >> 16) & 1u);
    return (ushort)(u >> 16);
}

// async global -> LDS, 16 bytes per lane (dest = uniform base + lane*16)
__device__ inline void glds16(const ushort* gsrc, ushort* ldsdst) {
    auto* g = (const __attribute__((address_space(1))) uint32_t*)gsrc;
    auto* l = (__attribute__((address_space(3))) uint32_t*)ldsdst;
    __builtin_amdgcn_global_load_lds(g, l, 16, 0, 0);
}

// inline-asm ds_read_b128: opaque to compiler alias analysis (no auto vmcnt)
__device__ inline short8 ds_read128(const ushort* p) {
    auto* l3 = (const __attribute__((address_space(3))) ushort*)p;
    const uint32_t addr = (uint32_t)(uintptr_t)l3;
    short8 v;
    asm volatile("ds_read_b128 %0, %1" : "=&v"(v) : "v"(addr));
    return v;
}

// ---------------------------------------------------------------------------
// Kernel 1: expmap0 + clip for embeddings. One wave (64 lanes) per row, D=512.
// ---------------------------------------------------------------------------
__global__ void rows_emb_kernel(const float* __restrict__ emb,
                                const float* __restrict__ logc,
                                float* __restrict__ xh,
                                ushort* __restrict__ xbf,
                                float* __restrict__ x2raw,
                                float* __restrict__ dxv) {
    const int D = 512;
    const int row = blockIdx.x;
    const int lane = threadIdx.x;   // 0..63

    const float4* r4 = (const float4*)(emb + (size_t)row * D);
    float4 a = r4[2 * lane];
    float4 b = r4[2 * lane + 1];

    float ss = a.x * a.x + a.y * a.y + a.z * a.z + a.w * a.w
             + b.x * b.x + b.y * b.y + b.z * b.z + b.w * b.w;
#pragma unroll
    for (int off = 32; off > 0; off >>= 1) ss += __shfl_xor(ss, off, 64);

    const float c  = expf(logc[0]);
    const float sc = sqrtf(c);

    const float tn    = sqrtf(ss);
    const float vn    = fmaxf(tn, EPSV);
    const float coeff = tanhf(sc * vn) / (sc * vn);
    const float pre   = coeff * tn;
    const float fac   = fminf(MAX_NORM / fmaxf(pre, EPSV), 1.0f);
    const float scale = coeff * fac;

    float4 oa, ob;
    oa.x = a.x * scale; oa.y = a.y * scale; oa.z = a.z * scale; oa.w = a.w * scale;
    ob.x = b.x * scale; ob.y = b.y * scale; ob.z = b.z * scale; ob.w = b.w * scale;

    float4* o4 = (float4*)(xh + (size_t)row * D);
    o4[2 * lane]     = oa;
    o4[2 * lane + 1] = ob;

    union { ushort u[8]; uint4 v; } pk;
    pk.u[0] = f32_to_bf16(oa.x); pk.u[1] = f32_to_bf16(oa.y);
    pk.u[2] = f32_to_bf16(oa.z); pk.u[3] = f32_to_bf16(oa.w);
    pk.u[4] = f32_to_bf16(ob.x); pk.u[5] = f32_to_bf16(ob.y);
    pk.u[6] = f32_to_bf16(ob.z); pk.u[7] = f32_to_bf16(ob.w);
    ((uint4*)(xbf + (size_t)row * D))[lane] = pk.v;

    if (lane == 0) {
        const float sq = scale * scale * ss;
        x2raw[row] = sq;
        dxv[row]   = 1.0f - c * fminf(sq, MAX_NORM * MAX_NORM);
    }
}

// ---------------------------------------------------------------------------
// Kernel 2: clip-only for centroids. One wave per row, D=512.
// ---------------------------------------------------------------------------
__global__ void rows_cen_kernel(const float* __restrict__ cen,
                                const float* __restrict__ logc,
                                float* __restrict__ ch,
                                ushort* __restrict__ cbf,
                                float* __restrict__ y2raw,
                                float* __restrict__ dyv) {
    const int D = 512;
    const int row = blockIdx.x;
    const int lane = threadIdx.x;

    const float4* r4 = (const float4*)(cen + (size_t)row * D);
    float4 a = r4[2 * lane];
    float4 b = r4[2 * lane + 1];

    float ss = a.x * a.x + a.y * a.y + a.z * a.z + a.w * a.w
             + b.x * b.x + b.y * b.y + b.z * b.z + b.w * b.w;
#pragma unroll
    for (int off = 32; off > 0; off >>= 1) ss += __shfl_xor(ss, off, 64);

    const float c = expf(logc[0]);

    const float tn    = sqrtf(ss);
    const float scale = fminf(MAX_NORM / fmaxf(tn, EPSV), 1.0f);

    float4 oa, ob;
    oa.x = a.x * scale; oa.y = a.y * scale; oa.z = a.z * scale; oa.w = a.w * scale;
    ob.x = b.x * scale; ob.y = b.y * scale; ob.z = b.z * scale; ob.w = b.w * scale;

    float4* o4 = (float4*)(ch + (size_t)row * D);
    o4[2 * lane]     = oa;
    o4[2 * lane + 1] = ob;

    union { ushort u[8]; uint4 v; } pk;
    pk.u[0] = f32_to_bf16(oa.x); pk.u[1] = f32_to_bf16(oa.y);
    pk.u[2] = f32_to_bf16(oa.z); pk.u[3] = f32_to_bf16(oa.w);
    pk.u[4] = f32_to_bf16(ob.x); pk.u[5] = f32_to_bf16(ob.y);
    pk.u[6] = f32_to_bf16(ob.z); pk.u[7] = f32_to_bf16(ob.w);
    ((uint4*)(cbf + (size_t)row * D))[lane] = pk.v;

    if (lane == 0) {
        const float sq = scale * scale * ss;
        y2raw[row] = sq;
        dyv[row]   = 1.0f - c * fminf(sq, MAX_NORM * MAX_NORM);
    }
}

// ---------------------------------------------------------------------------
// Kernel 3: bf16 MFMA GEMM + Poincare epilogue.  RING-OF-4 PIPELINE.
// 256x256 tile, BKT=32, 8 waves (2Mx4N, each 128x64 = 8x4 frags).
// LDS = 4 ring buffers x 32KB (A 16KB + B 16KB), fragment-order subtiles
// (zero-conflict ds_read). Depth-3 prefetch, ONE barrier + one counted
// vmcnt(8) per K-tile; staging of tile t+3 spread through tile t's four
// MFMA quadrants; quadrant lgkmcnt(2) hides ds_read latency under MFMA.
// Ring invariant: buf[(t+3)&3] = buf[(t-1)&3]; the top-of-iteration barrier
// proves all waves finished reading tile t-1, so overwrite is race-free.
// Epilogue: per-wave LDS transpose + float4-coalesced stores.
// ---------------------------------------------------------------------------
#define BM 256
#define BN 256
#define BKT 32
#define EPST 68   // epilogue LDS row stride in floats

__global__ __launch_bounds__(512, 2)
void gemm_epi_kernel(const ushort* __restrict__ Abf,   // M x K bf16
                     const ushort* __restrict__ Bbf,   // N x K bf16
                     const float* __restrict__ x2raw,
                     const float* __restrict__ dxv,
                     const float* __restrict__ y2raw,
                     const float* __restrict__ dyv,
                     const float* __restrict__ logc,
                     float* __restrict__ out,          // M x N
                     int M, int N, int K) {
    __shared__ __align__(16) char smem[4 * 32768];   // 128 KB ring

    const int tid  = threadIdx.x;
    const int lane = tid & 63;
    const int wid  = tid >> 6;     // 0..7
    const int wm   = wid >> 2;     // 0..1  (128-row half)
    const int wn   = wid & 3;      // 0..3  (64-col quarter)

    const int bm = blockIdx.y;
    const int bn = blockIdx.x;

    const ushort* Ab = Abf + (size_t)bm * BM * K;
    const ushort* Bb = Bbf + (size_t)bn * BN * K;

    f32x4 acc[8][4];
#pragma unroll
    for (int m = 0; m < 8; m++)
#pragma unroll
        for (int n = 0; n < 4; n++) acc[m][n] = (f32x4){0.f, 0.f, 0.f, 0.f};

    // Per-lane fragment-order source offset within a 16x32 subtile.
    const size_t fragoff = (size_t)(lane & 15) * K + ((lane >> 4) * 8);

    auto Abuf = [&](int b) { return (ushort*)(smem + b * 32768); };
    auto Bbuf = [&](int b) { return (ushort*)(smem + b * 32768 + 16384); };

    // One staging call (j=0..3) for the K-tile at k0 into ring buffer b.
    // j0/j1: A subtiles 2w,2w+1; j2/j3: B subtiles 2w,2w+1. 4 calls = 1 tile.
    auto stage_call = [&](int b, int k0, int j) {
        const int s = wid * 2 + (j & 1);
        const size_t goff = (size_t)(s * 16) * K + k0 + fragoff;
        if (j < 2) glds16(Ab + goff, Abuf(b) + s * 512);
        else       glds16(Bb + goff, Bbuf(b) + s * 512);
    };

    const int NT = K / BKT;          // 16

    // Prologue: stage tiles 0,1,2 (12 wave-loads outstanding).
#pragma unroll
    for (int tt = 0; tt < 3; ++tt)
#pragma unroll
        for (int j = 0; j < 4; ++j)
            stage_call(tt & 3, tt * BKT, j);

    for (int t = 0; t < NT; ++t) {
        const int b = t & 3;

        // Drain exactly tile t's 4 loads (12 outstanding in steady state).
        if (t <= NT - 3)      asm volatile("s_waitcnt vmcnt(8)" ::: "memory");
        else if (t == NT - 2) asm volatile("s_waitcnt vmcnt(4)" ::: "memory");
        else                  asm volatile("s_waitcnt vmcnt(0)" ::: "memory");
        __builtin_amdgcn_s_barrier();   // publish buf[b]; tile t-1 reads done

        const bool do_stage = (t + 3 < NT);
        const int  sb = (t + 3) & 3;
        const int  sk = (t + 3) * BKT;

        short8 af[8], bfr[4];
#pragma unroll
        for (int n = 0; n < 4; n++)
            bfr[n] = ds_read128(Bbuf(b) + (wn * 4 + n) * 512 + lane * 8);
        af[0] = ds_read128(Abuf(b) + (wm * 8 + 0) * 512 + lane * 8);
        af[1] = ds_read128(Abuf(b) + (wm * 8 + 1) * 512 + lane * 8);

#pragma unroll
        for (int q = 0; q < 4; ++q) {
            if (do_stage) stage_call(sb, sk, q);   // 1 of 4 stage calls/quadrant
            if (q < 3) {
                af[2 * q + 2] = ds_read128(Abuf(b) + (wm * 8 + 2 * q + 2) * 512 + lane * 8);
                af[2 * q + 3] = ds_read128(Abuf(b) + (wm * 8 + 2 * q + 3) * 512 + lane * 8);
                asm volatile("s_waitcnt lgkmcnt(2)" ::: "memory");  // cur quadrant ready
            } else {
                asm volatile("s_waitcnt lgkmcnt(0)" ::: "memory");
            }
            __builtin_amdgcn_sched_barrier(0);     // rule #18
            __builtin_amdgcn_s_setprio(1);
#pragma unroll
            for (int mm = 0; mm < 2; mm++)
#pragma unroll
                for (int n = 0; n < 4; n++)
                    acc[2 * q + mm][n] = __builtin_amdgcn_mfma_f32_16x16x32_bf16(
                        af[2 * q + mm], bfr[n], acc[2 * q + mm][n], 0, 0, 0);
            __builtin_amdgcn_s_setprio(0);
        }
        // no end-of-iteration barrier: next iteration's top barrier covers it
    }

    __syncthreads();   // staging LDS -> epilogue reuse safety

    // ---------------- Epilogue: LDS transpose + coalesced stores ------------
    const float c   = expf(logc[0]);
    const float rsc = 1.0f / sqrtf(c);
    const int l16 = lane & 15;
    const int lg  = lane >> 4;

    float* ep = (float*)(smem + (size_t)wid * 4352);  // private [16][EPST]
    const int gr_base = bm * BM + wm * 128;
    const int gc_base = bn * BN + wn * 64;

#pragma unroll
    for (int m = 0; m < 8; m++) {
        // scatter this m-frag (16 rows x 64 cols) into the private region
#pragma unroll
        for (int n = 0; n < 4; n++)
#pragma unroll
            for (int r = 0; r < 4; r++)
                ep[(lg * 4 + r) * EPST + n * 16 + l16] = acc[m][n][r];
        asm volatile("s_waitcnt lgkmcnt(0)" ::: "memory");

        // read back row-major: 4 iters x (4 rows x 16 float4 chunks)
#pragma unroll
        for (int it = 0; it < 4; it++) {
            const int row = it * 4 + lg;                  // 0..15
            const int gr  = gr_base + m * 16 + row;
            const int gc  = gc_base + l16 * 4;
            float4 xy4 = *(const float4*)&ep[row * EPST + l16 * 4];
            const float rx  = x2raw[gr];
            const float dxr = dxv[gr];
            const float4 ry4 = *(const float4*)&y2raw[gc];
            const float4 dy4 = *(const float4*)&dyv[gc];
            float4 o;
            {
                const float rden = __builtin_amdgcn_rcpf(fmaxf(dxr * dy4.x, EPSV));
                float t = fmaxf(2.0f * c * (rx + ry4.x - 2.0f * xy4.x) * rden, EPSV);
                o.x = __logf(1.0f + t + __builtin_amdgcn_sqrtf(t * (t + 2.0f))) * rsc;
            }
            {
                const float rden = __builtin_amdgcn_rcpf(fmaxf(dxr * dy4.y, EPSV));
                float t = fmaxf(2.0f * c * (rx + ry4.y - 2.0f * xy4.y) * rden, EPSV);
                o.y = __logf(1.0f + t + __builtin_amdgcn_sqrtf(t * (t + 2.0f))) * rsc;
            }
            {
                const float rden = __builtin_amdgcn_rcpf(fmaxf(dxr * dy4.z, EPSV));
                float t = fmaxf(2.0f * c * (rx + ry4.z - 2.0f * xy4.z) * rden, EPSV);
                o.z = __logf(1.0f + t + __builtin_amdgcn_sqrtf(t * (t + 2.0f))) * rsc;
            }
            {
                const float rden = __builtin_amdgcn_rcpf(fmaxf(dxr * dy4.w, EPSV));
                float t = fmaxf(2.0f * c * (rx + ry4.w - 2.0f * xy4.w) * rden, EPSV);
                o.w = __logf(1.0f + t + __builtin_amdgcn_sqrtf(t * (t + 2.0f))) * rsc;
            }
            *(float4*)&out[(size_t)gr * N + gc] = o;
        }
        asm volatile("s_waitcnt lgkmcnt(0)" ::: "memory");
    }
}

// ---------------------------------------------------------------------------
extern "C" void kernel_launch(void* const* d_in, const int* in_sizes, int n_in,
                              void* d_out, int out_size, void* d_ws, size_t ws_size,
                              hipStream_t stream) {
    const float* emb  = (const float*)d_in[0];   // (B, D) f32
    const float* logc = (const float*)d_in[1];   // scalar f32
    const float* cen  = (const float*)d_in[2];   // (C, D) f32

    const int D = 512;
    const int B = in_sizes[0] / D;   // 8192
    const int C = in_sizes[2] / D;   // 4096

    float* out   = (float*)d_out;
    float* dists = out;                          // B*C
    float* xh    = out + (size_t)B * C;          // B*D
    float* ch    = xh + (size_t)B * D;           // C*D

    char* ws = (char*)d_ws;
    size_t off = 0;
    auto alloc = [&](size_t bytes) -> char* {
        char* p = ws + off;
        off += (bytes + 255) & ~(size_t)255;
        return p;
    };
    ushort* xbf   = (ushort*)alloc((size_t)B * D * sizeof(ushort));
    ushort* cbf   = (ushort*)alloc((size_t)C * D * sizeof(ushort));
    float*  x2raw = (float*)alloc((size_t)B * sizeof(float));
    float*  dxv   = (float*)alloc((size_t)B * sizeof(float));
    float*  y2raw = (float*)alloc((size_t)C * sizeof(float));
    float*  dyv   = (float*)alloc((size_t)C * sizeof(float));

    rows_emb_kernel<<<B, 64, 0, stream>>>(emb, logc, xh, xbf, x2raw, dxv);
    rows_cen_kernel<<<C, 64, 0, stream>>>(cen, logc, ch, cbf, y2raw, dyv);

    dim3 grid(C / BN, B / BM);   // (16, 32)
    gemm_epi_kernel<<<grid, 512, 0, stream>>>(xbf, cbf, x2raw, dxv, y2raw, dyv,
                                              logc, dists, B, C, D);
}